// Round 2
// baseline (498.095 us; speedup 1.0000x reference)
//
#include <hip/hip_runtime.h>
#include <hip/hip_bf16.h>

#define M_NODES 16384
#define E_EDGES 524288

static __device__ __forceinline__ float wredsum(float v) {
#pragma unroll
  for (int o = 32; o > 0; o >>= 1) v += __shfl_xor(v, o, 64);
  return v;
}

static __device__ __forceinline__ float gelu_exact(float x) {
  return 0.5f * x * (1.0f + erff(x * 0.70710678118654752440f));
}

// ---------------------------------------------------------------------------
// K0: decode x -> (grid2, gwf), h0 = LN(feat @ fc0_w.T + b), hl0 = h0 @ W1[0].T + b1[0]
// one wave per node, lane = channel
// ---------------------------------------------------------------------------
__global__ __launch_bounds__(256) void k_init(
    const float* __restrict__ x,
    const float* __restrict__ fc0_w, const float* __restrict__ fc0_b,
    const float* __restrict__ ln0_g, const float* __restrict__ ln0_b,
    const float* __restrict__ w1, const float* __restrict__ b1,
    float2* __restrict__ grid2, float* __restrict__ gwf,
    float* __restrict__ h, float* __restrict__ hl)
{
  __shared__ float WL[64 * 65];   // gg_fc1_w[0], padded stride 65 -> 2-way bank alias (free)
  const int tid = threadIdx.x;
  for (int i = tid; i < 4096; i += 256) WL[(i >> 6) * 65 + (i & 63)] = w1[i];
  __syncthreads();

  const int lane = tid & 63;
  const int node = blockIdx.x * 4 + (tid >> 6);

  float xv[5];
#pragma unroll
  for (int k = 0; k < 5; ++k) xv[k] = x[node * 5 + k];

  float acc = fc0_b[lane];
#pragma unroll
  for (int k = 0; k < 4; ++k) acc += xv[k] * fc0_w[lane * 4 + k];

  float mean = wredsum(acc) * (1.0f / 64.0f);
  float d = acc - mean;
  float var = wredsum(d * d) * (1.0f / 64.0f);
  float hv = d * rsqrtf(var + 1e-5f) * ln0_g[lane] + ln0_b[lane];
  h[node * 64 + lane] = hv;

  if (lane == 0) { grid2[node] = make_float2(xv[2], xv[3]); gwf[node] = xv[4]; }

  float acc2 = b1[lane];
#pragma unroll
  for (int k = 0; k < 64; ++k) acc2 += __shfl(hv, k, 64) * WL[lane * 65 + k];
  hl[node * 64 + lane] = acc2;
}

// ---------------------------------------------------------------------------
// counting sort of edges by dst
// ---------------------------------------------------------------------------
__global__ __launch_bounds__(256) void k_count(const int* __restrict__ ei, int* __restrict__ cnt)
{
  int e = blockIdx.x * 256 + threadIdx.x;
  if (e < E_EDGES) atomicAdd(&cnt[ei[E_EDGES + e]], 1);
}

__global__ __launch_bounds__(1024) void k_scan(const int* __restrict__ cnt,
                                               int* __restrict__ row_start,
                                               int* __restrict__ cursor)
{
  const int PER = M_NODES / 1024;   // 16
  const int t = threadIdx.x;
  const int base = t * PER;
  int local[PER];
  int s = 0;
#pragma unroll
  for (int k = 0; k < PER; ++k) { local[k] = cnt[base + k]; s += local[k]; }

  __shared__ int part[1024];
  part[t] = s;
  __syncthreads();
  for (int off = 1; off < 1024; off <<= 1) {
    int v = (t >= off) ? part[t - off] : 0;
    __syncthreads();
    part[t] += v;
    __syncthreads();
  }
  int run = part[t] - s;   // exclusive prefix of this thread's chunk
#pragma unroll
  for (int k = 0; k < PER; ++k) {
    row_start[base + k] = run;
    cursor[base + k] = run;
    run += local[k];
  }
  if (t == 1023) row_start[M_NODES] = run;
}

// record = (vec.x, vec.y, wgt_src, src_as_float_bits)
__global__ __launch_bounds__(256) void k_scatter(
    const int* __restrict__ ei, const float2* __restrict__ grid2,
    const float* __restrict__ gwf, int* __restrict__ cursor,
    float4* __restrict__ rec)
{
  int e = blockIdx.x * 256 + threadIdx.x;
  if (e < E_EDGES) {
    int s = ei[e];
    int dd = ei[E_EDGES + e];
    int pos = atomicAdd(&cursor[dd], 1);
    float2 gs = grid2[s], gd = grid2[dd];
    rec[pos] = make_float4(gs.x - gd.x, gs.y - gd.y, gwf[s], __int_as_float(s));
  }
}

// ---------------------------------------------------------------------------
// edge aggregation: agg[n][j] = sum_e morlet(e,j) * hl[src_e][j] * wgt(e)
// one wave per dst node; lane = channel; edges sorted by dst -> register acc
// ---------------------------------------------------------------------------
__global__ __launch_bounds__(256) void k_agg(
    const float4* __restrict__ rec, const int* __restrict__ row_start,
    const float* __restrict__ hl,
    const float* __restrict__ gw, const float* __restrict__ freq,
    float* __restrict__ agg)
{
  const int lane = threadIdx.x & 63;
  const int node = blockIdx.x * 4 + (threadIdx.x >> 6);

  const float w = gw[lane];
  const float coef = fabsf(w) * 0.31830988618379067f;  // sqrt((w/pi)^2) = |w|/pi (PHY=2)
  const float f0 = freq[lane];
  const float f1 = freq[64 + lane];

  const int beg = row_start[node];
  const int end = row_start[node + 1];
  float acc = 0.0f;
  for (int i = beg; i < end; ++i) {
    float4 r = rec[i];                       // broadcast 16B load
    int src = __float_as_int(r.w);
    float hlv = hl[src * 64 + lane];         // coalesced 256B gather
    float dist2 = r.x * r.x + r.y * r.y;
    float gs = coef * expf(-w * dist2);
    float fo = sinf(r.x * f0 + r.y * f1);
    acc += gs * fo * hlv * r.z;
  }
  agg[node * 64 + lane] = acc;
}

// ---------------------------------------------------------------------------
// post (layers 0,1): h = gelu(LN(agg@W2.T + b2 + h@Wc.T + bc)); hl = h@W1[l+1].T + b1[l+1]
// ---------------------------------------------------------------------------
__global__ __launch_bounds__(256) void k_post_mid(
    const float* __restrict__ agg, float* __restrict__ h, float* __restrict__ hl,
    const float* __restrict__ fc2w, const float* __restrict__ fc2b,
    const float* __restrict__ wcw, const float* __restrict__ wcb,
    const float* __restrict__ lng, const float* __restrict__ lnb,
    const float* __restrict__ nw1, const float* __restrict__ nb1)
{
  __shared__ float WS[8320];  // [64][129] concat(fc2w|wcw), then reused as [64][65]
  const int tid = threadIdx.x;
  for (int i = tid; i < 8192; i += 256) {
    int c = i >> 7, k = i & 127;
    WS[c * 129 + k] = (k < 64) ? fc2w[c * 64 + k] : wcw[c * 64 + (k - 64)];
  }
  __syncthreads();

  const int lane = tid & 63;
  const int node = blockIdx.x * 4 + (tid >> 6);

  float av = agg[node * 64 + lane];
  float hvold = h[node * 64 + lane];

  float acc = fc2b[lane] + wcb[lane];
#pragma unroll
  for (int k = 0; k < 64; ++k) {
    acc += __shfl(av, k, 64) * WS[lane * 129 + k];
    acc += __shfl(hvold, k, 64) * WS[lane * 129 + 64 + k];
  }
  float mean = wredsum(acc) * (1.0f / 64.0f);
  float d = acc - mean;
  float var = wredsum(d * d) * (1.0f / 64.0f);
  float hv = d * rsqrtf(var + 1e-5f) * lng[lane] + lnb[lane];
  hv = gelu_exact(hv);
  h[node * 64 + lane] = hv;

  __syncthreads();
  for (int i = tid; i < 4096; i += 256) WS[(i >> 6) * 65 + (i & 63)] = nw1[i];
  __syncthreads();

  float acc2 = nb1[lane];
#pragma unroll
  for (int k = 0; k < 64; ++k) acc2 += __shfl(hv, k, 64) * WS[lane * 65 + k];
  hl[node * 64 + lane] = acc2;
}

// ---------------------------------------------------------------------------
// post (layer 2) + head: h = LN(x1+x2); t = gelu(h@fc1.T+b); out = t@fc2.T+b
// ---------------------------------------------------------------------------
__global__ __launch_bounds__(256) void k_post_last(
    const float* __restrict__ agg, const float* __restrict__ h,
    const float* __restrict__ fc2w, const float* __restrict__ fc2b,
    const float* __restrict__ wcw, const float* __restrict__ wcb,
    const float* __restrict__ lng, const float* __restrict__ lnb,
    const float* __restrict__ fc1w, const float* __restrict__ fc1b,
    const float* __restrict__ fw2, const float* __restrict__ fb2,
    float* __restrict__ out)
{
  __shared__ float WS[8320];  // [64][129] concat, then [128][65] fc1_w
  const int tid = threadIdx.x;
  for (int i = tid; i < 8192; i += 256) {
    int c = i >> 7, k = i & 127;
    WS[c * 129 + k] = (k < 64) ? fc2w[c * 64 + k] : wcw[c * 64 + (k - 64)];
  }
  __syncthreads();

  const int lane = tid & 63;
  const int node = blockIdx.x * 4 + (tid >> 6);

  float av = agg[node * 64 + lane];
  float hvold = h[node * 64 + lane];

  float acc = fc2b[lane] + wcb[lane];
#pragma unroll
  for (int k = 0; k < 64; ++k) {
    acc += __shfl(av, k, 64) * WS[lane * 129 + k];
    acc += __shfl(hvold, k, 64) * WS[lane * 129 + 64 + k];
  }
  float mean = wredsum(acc) * (1.0f / 64.0f);
  float d = acc - mean;
  float var = wredsum(d * d) * (1.0f / 64.0f);
  float hv = d * rsqrtf(var + 1e-5f) * lng[lane] + lnb[lane];
  // no gelu on last layer's h

  __syncthreads();
  for (int i = tid; i < 8192; i += 256) WS[(i >> 6) * 65 + (i & 63)] = fc1w[i];
  __syncthreads();

  float t0 = fc1b[lane];
  float t1 = fc1b[lane + 64];
#pragma unroll
  for (int k = 0; k < 64; ++k) {
    float hk = __shfl(hv, k, 64);
    t0 += hk * WS[lane * 65 + k];
    t1 += hk * WS[(lane + 64) * 65 + k];
  }
  t0 = gelu_exact(t0);
  t1 = gelu_exact(t1);
  float p = t0 * fw2[lane] + t1 * fw2[lane + 64];
  float s = wredsum(p);
  if (lane == 0) out[node] = s + fb2[0];
}

// ---------------------------------------------------------------------------
extern "C" void kernel_launch(void* const* d_in, const int* in_sizes, int n_in,
                              void* d_out, int out_size, void* d_ws, size_t ws_size,
                              hipStream_t stream) {
  const float* x     = (const float*)d_in[0];
  const int* ei      = (const int*)d_in[1];
  const float* fc0_w = (const float*)d_in[2];
  const float* fc0_b = (const float*)d_in[3];
  const float* ln0_g = (const float*)d_in[4];
  const float* ln0_b = (const float*)d_in[5];
  const float* gg_fc1_w = (const float*)d_in[6];
  const float* gg_fc1_b = (const float*)d_in[7];
  const float* gg_fc2_w = (const float*)d_in[8];
  const float* gg_fc2_b = (const float*)d_in[9];
  const float* gg_weight = (const float*)d_in[10];
  const float* gg_freq   = (const float*)d_in[11];
  const float* wc_w = (const float*)d_in[12];
  const float* wc_b = (const float*)d_in[13];
  const float* ln_g = (const float*)d_in[14];
  const float* ln_b = (const float*)d_in[15];
  const float* fc1_w = (const float*)d_in[16];
  const float* fc1_b = (const float*)d_in[17];
  const float* fc2_w = (const float*)d_in[18];
  const float* fc2_b = (const float*)d_in[19];

  char* ws = (char*)d_ws;
  size_t off = 0;
  auto alloc = [&](size_t bytes) -> void* {
    void* p = ws + off;
    off = (off + bytes + 255) & ~(size_t)255;
    return p;
  };
  float2* grid2   = (float2*)alloc((size_t)M_NODES * 8);
  float*  gwf     = (float*)alloc((size_t)M_NODES * 4);
  float*  h       = (float*)alloc((size_t)M_NODES * 64 * 4);
  float*  hl      = (float*)alloc((size_t)M_NODES * 64 * 4);
  float*  agg     = (float*)alloc((size_t)M_NODES * 64 * 4);
  int*    cnt     = (int*)alloc((size_t)M_NODES * 4);
  int*    cursor  = (int*)alloc((size_t)M_NODES * 4);
  int*    row_st  = (int*)alloc((size_t)(M_NODES + 1) * 4);
  float4* rec     = (float4*)alloc((size_t)E_EDGES * 16);
  (void)ws_size; (void)in_sizes; (void)n_in; (void)out_size;

  hipMemsetAsync(cnt, 0, (size_t)M_NODES * 4, stream);

  k_init<<<M_NODES / 4, 256, 0, stream>>>(x, fc0_w, fc0_b, ln0_g, ln0_b,
                                          gg_fc1_w, gg_fc1_b, grid2, gwf, h, hl);
  k_count<<<E_EDGES / 256, 256, 0, stream>>>(ei, cnt);
  k_scan<<<1, 1024, 0, stream>>>(cnt, row_st, cursor);
  k_scatter<<<E_EDGES / 256, 256, 0, stream>>>(ei, grid2, gwf, cursor, rec);

  for (int l = 0; l < 3; ++l) {
    k_agg<<<M_NODES / 4, 256, 0, stream>>>(rec, row_st, hl,
                                           gg_weight + l * 64, gg_freq + l * 128, agg);
    if (l < 2) {
      k_post_mid<<<M_NODES / 4, 256, 0, stream>>>(
          agg, h, hl,
          gg_fc2_w + l * 4096, gg_fc2_b + l * 64,
          wc_w + l * 4096, wc_b + l * 64,
          ln_g + l * 64, ln_b + l * 64,
          gg_fc1_w + (l + 1) * 4096, gg_fc1_b + (l + 1) * 64);
    } else {
      k_post_last<<<M_NODES / 4, 256, 0, stream>>>(
          agg, h,
          gg_fc2_w + l * 4096, gg_fc2_b + l * 64,
          wc_w + l * 4096, wc_b + l * 64,
          ln_g + l * 64, ln_b + l * 64,
          fc1_w, fc1_b, fc2_w, fc2_b,
          (float*)d_out);
    }
  }
}

// Round 3
// 366.757 us; speedup vs baseline: 1.3581x; 1.3581x over previous
//
#include <hip/hip_runtime.h>
#include <hip/hip_bf16.h>

#define M_NODES 16384
#define E_EDGES 524288
#define ASTR 68   // uint stride of LDS A rows: 2-way bank alias only (free), 16B-aligned rows

typedef short short8 __attribute__((ext_vector_type(8)));
typedef float f32x4 __attribute__((ext_vector_type(4)));
typedef unsigned int uint4v __attribute__((ext_vector_type(4)));

static __device__ __forceinline__ float wredsum(float v) {
#pragma unroll
  for (int o = 32; o > 0; o >>= 1) v += __shfl_xor(v, o, 64);
  return v;
}

static __device__ __forceinline__ float gelu_exact(float x) {
  return 0.5f * x * (1.0f + erff(x * 0.70710678118654752440f));
}

// split fp32 -> (bf16 hi | bf16 lo) packed in one uint (hi in low 16, lo in high 16)
static __device__ __forceinline__ unsigned int bsplit(float x) {
  unsigned int u = __float_as_uint(x);
  unsigned int hb = (u + 0x7FFFu + ((u >> 16) & 1u)) >> 16;   // RNE bf16 of x
  float hf = __uint_as_float(hb << 16);
  float r = x - hf;
  unsigned int v = __float_as_uint(r);
  unsigned int lb = (v + 0x7FFFu + ((v >> 16) & 1u)) >> 16;   // RNE bf16 of residual
  return (hb & 0xFFFFu) | (lb << 16);
}

struct Frag { short8 hi, lo; };

// 8 consecutive packed uints (16B aligned) -> hi/lo bf16 fragments
static __device__ __forceinline__ Frag load_afrag(const unsigned int* a) {
  uint4v u0 = *(const uint4v*)a;
  uint4v u1 = *(const uint4v*)(a + 4);
  Frag f;
#pragma unroll
  for (int j = 0; j < 4; ++j) {
    f.hi[j]     = (short)(u0[j] & 0xFFFFu);
    f.lo[j]     = (short)(u0[j] >> 16);
    f.hi[j + 4] = (short)(u1[j] & 0xFFFFu);
    f.lo[j + 4] = (short)(u1[j] >> 16);
  }
  return f;
}

// 8 consecutive fp32 from global (32B aligned) -> hi/lo fragments
static __device__ __forceinline__ Frag load_bfrag(const float* __restrict__ w) {
  float4 w0 = *(const float4*)w;
  float4 w1 = *(const float4*)(w + 4);
  float v[8] = {w0.x, w0.y, w0.z, w0.w, w1.x, w1.y, w1.z, w1.w};
  Frag f;
#pragma unroll
  for (int j = 0; j < 8; ++j) {
    unsigned int p = bsplit(v[j]);
    f.hi[j] = (short)(p & 0xFFFFu);
    f.lo[j] = (short)(p >> 16);
  }
  return f;
}

static __device__ __forceinline__ f32x4 mfma3(const Frag& a, const Frag& b, f32x4 c) {
  c = __builtin_amdgcn_mfma_f32_16x16x32_bf16(a.hi, b.hi, c, 0, 0, 0);
  c = __builtin_amdgcn_mfma_f32_16x16x32_bf16(a.lo, b.hi, c, 0, 0, 0);
  c = __builtin_amdgcn_mfma_f32_16x16x32_bf16(a.hi, b.lo, c, 0, 0, 0);
  return c;
}

// D[m][n] = sum_k A[m][k] * W[n][k] for one wave's 16-node tile, 64 outputs.
// Arow = LDS packed row of this lane's m (= Abase + (rowbase + (lane&15))*ASTR).
// W row-major [>=64][64] fp32. acc[t]: n-tile t (cols 16t + (lane&15)).
static __device__ __forceinline__ void gemm64(const unsigned int* Arow,
                                              const float* __restrict__ W,
                                              int c, int q, f32x4 acc[4]) {
  Frag a0 = load_afrag(Arow + 8 * q);        // k-step 0: k = 8q + j
  Frag a1 = load_afrag(Arow + 32 + 8 * q);   // k-step 1: k = 32 + 8q + j
#pragma unroll
  for (int t = 0; t < 4; ++t) {
    Frag b0 = load_bfrag(W + (16 * t + c) * 64 + 8 * q);
    Frag b1 = load_bfrag(W + (16 * t + c) * 64 + 32 + 8 * q);
    acc[t] = mfma3(a0, b0, acc[t]);
    acc[t] = mfma3(a1, b1, acc[t]);
  }
}

// store D + bias[n] to O[node*64 + n]; D layout: col = 16t+c, row = 4q+r
static __device__ __forceinline__ void store_d(float* __restrict__ O,
                                               const float* __restrict__ bias,
                                               int tilebase, int c, int q,
                                               const f32x4 acc[4]) {
#pragma unroll
  for (int t = 0; t < 4; ++t) {
    float bn = bias[16 * t + c];
#pragma unroll
    for (int r = 0; r < 4; ++r)
      O[(tilebase + 4 * q + r) * 64 + 16 * t + c] = acc[t][r] + bn;
  }
}

// ---------------------------------------------------------------------------
// k_init: h0 = LN(feat@fc0.T+b) per-lane; then MFMA: hl0 = h0@W1[0].T+b1,
// x2_0 = h0@Wc[0].T+wcb. Block = 4 waves = 64 nodes.
// ---------------------------------------------------------------------------
__global__ __launch_bounds__(256) void k_init(
    const float* __restrict__ x,
    const float* __restrict__ fc0_w, const float* __restrict__ fc0_b,
    const float* __restrict__ ln0_g, const float* __restrict__ ln0_b,
    const float* __restrict__ w1, const float* __restrict__ b1,
    const float* __restrict__ wc, const float* __restrict__ wcb,
    float2* __restrict__ grid2, float* __restrict__ gwf,
    float* __restrict__ hl, float* __restrict__ x2)
{
  __shared__ unsigned int A[64 * ASTR];
  const int tid = threadIdx.x;
  const int lane = tid & 63;
  const int w = tid >> 6;
  const int tilebase = blockIdx.x * 64 + w * 16;

  float fw0 = fc0_w[lane * 4 + 0], fw1 = fc0_w[lane * 4 + 1];
  float fw2v = fc0_w[lane * 4 + 2], fw3 = fc0_w[lane * 4 + 3];
  float fb = fc0_b[lane], g0 = ln0_g[lane], bb0 = ln0_b[lane];

  for (int i = 0; i < 16; ++i) {
    int node = tilebase + i;
    float xv0 = x[node * 5 + 0], xv1 = x[node * 5 + 1], xv2 = x[node * 5 + 2];
    float xv3 = x[node * 5 + 3], xv4 = x[node * 5 + 4];
    float acc = fb + xv0 * fw0 + xv1 * fw1 + xv2 * fw2v + xv3 * fw3;
    float mean = wredsum(acc) * (1.0f / 64.0f);
    float d = acc - mean;
    float var = wredsum(d * d) * (1.0f / 64.0f);
    float hv = d * rsqrtf(var + 1e-5f) * g0 + bb0;
    A[(w * 16 + i) * ASTR + lane] = bsplit(hv);
    if (lane == 0) { grid2[node] = make_float2(xv2, xv3); gwf[node] = xv4; }
  }
  __syncthreads();

  const int c = lane & 15, q = lane >> 4;
  const unsigned int* Arow = A + (w * 16 + c) * ASTR;

  f32x4 z = {0.f, 0.f, 0.f, 0.f};
  f32x4 acc1[4] = {z, z, z, z};
  gemm64(Arow, w1, c, q, acc1);
  store_d(hl, b1, tilebase, c, q, acc1);

  f32x4 acc2[4] = {z, z, z, z};
  gemm64(Arow, wc, c, q, acc2);
  store_d(x2, wcb, tilebase, c, q, acc2);
}

// ---------------------------------------------------------------------------
// counting sort of edges by dst (unchanged)
// ---------------------------------------------------------------------------
__global__ __launch_bounds__(256) void k_count(const int* __restrict__ ei, int* __restrict__ cnt)
{
  int e = blockIdx.x * 256 + threadIdx.x;
  if (e < E_EDGES) atomicAdd(&cnt[ei[E_EDGES + e]], 1);
}

__global__ __launch_bounds__(1024) void k_scan(const int* __restrict__ cnt,
                                               int* __restrict__ row_start,
                                               int* __restrict__ cursor)
{
  const int PER = M_NODES / 1024;   // 16
  const int t = threadIdx.x;
  const int base = t * PER;
  int local[PER];
  int s = 0;
#pragma unroll
  for (int k = 0; k < PER; ++k) { local[k] = cnt[base + k]; s += local[k]; }

  __shared__ int part[1024];
  part[t] = s;
  __syncthreads();
  for (int off = 1; off < 1024; off <<= 1) {
    int v = (t >= off) ? part[t - off] : 0;
    __syncthreads();
    part[t] += v;
    __syncthreads();
  }
  int run = part[t] - s;
#pragma unroll
  for (int k = 0; k < PER; ++k) {
    row_start[base + k] = run;
    cursor[base + k] = run;
    run += local[k];
  }
  if (t == 1023) row_start[M_NODES] = run;
}

__global__ __launch_bounds__(256) void k_scatter(
    const int* __restrict__ ei, const float2* __restrict__ grid2,
    const float* __restrict__ gwf, int* __restrict__ cursor,
    float4* __restrict__ rec)
{
  int e = blockIdx.x * 256 + threadIdx.x;
  if (e < E_EDGES) {
    int s = ei[e];
    int dd = ei[E_EDGES + e];
    int pos = atomicAdd(&cursor[dd], 1);
    float2 gs = grid2[s], gd = grid2[dd];
    rec[pos] = make_float4(gs.x - gd.x, gs.y - gd.y, gwf[s], __int_as_float(s));
  }
}

// ---------------------------------------------------------------------------
// edge aggregation (unchanged): one wave per dst node, lane = channel
// ---------------------------------------------------------------------------
__global__ __launch_bounds__(256) void k_agg(
    const float4* __restrict__ rec, const int* __restrict__ row_start,
    const float* __restrict__ hl,
    const float* __restrict__ gw, const float* __restrict__ freq,
    float* __restrict__ agg)
{
  const int lane = threadIdx.x & 63;
  const int node = blockIdx.x * 4 + (threadIdx.x >> 6);

  const float w = gw[lane];
  const float coef = fabsf(w) * 0.31830988618379067f;  // |w|/pi (PHY=2)
  const float f0 = freq[lane];
  const float f1 = freq[64 + lane];

  const int beg = row_start[node];
  const int end = row_start[node + 1];
  float acc = 0.0f;
  for (int i = beg; i < end; ++i) {
    float4 r = rec[i];
    int src = __float_as_int(r.w);
    float hlv = hl[src * 64 + lane];
    float dist2 = r.x * r.x + r.y * r.y;
    float gs = coef * expf(-w * dist2);
    float fo = sinf(r.x * f0 + r.y * f1);
    acc += gs * fo * hlv * r.z;
  }
  agg[node * 64 + lane] = acc;
}

// ---------------------------------------------------------------------------
// post (layers 0,1): S = agg@W2.T + b2 + x2 ; h = gelu(LN(S));
// then hl = h@W1next.T + b1next ; x2 = h@Wcnext.T + wcbnext
// ---------------------------------------------------------------------------
__global__ __launch_bounds__(256) void k_post_mid(
    const float* __restrict__ agg,
    const float* __restrict__ w2, const float* __restrict__ b2,
    const float* __restrict__ lng, const float* __restrict__ lnb,
    const float* __restrict__ nw1, const float* __restrict__ nb1,
    const float* __restrict__ nwc, const float* __restrict__ nwcb,
    float* __restrict__ hl, float* __restrict__ x2)
{
  __shared__ unsigned int A[64 * ASTR];
  const int tid = threadIdx.x, lane = tid & 63, w = tid >> 6;
  const int tilebase = blockIdx.x * 64 + w * 16;
  const int c = lane & 15, q = lane >> 4;

  // early prefetch: x2 + LN params + bias (consumed in epilogue)
  float x2v[4][4], lg[4], lb[4], vb[4];
#pragma unroll
  for (int t = 0; t < 4; ++t) {
    int n = 16 * t + c;
    lg[t] = lng[n]; lb[t] = lnb[n]; vb[t] = b2[n];
#pragma unroll
    for (int r = 0; r < 4; ++r)
      x2v[t][r] = x2[(tilebase + 4 * q + r) * 64 + n];
  }

  // stage agg rows (wave-private): lane -> row 16w + (lane>>2), 16 cols
  {
    int rr = lane >> 2, cc = (lane & 3) * 16;
    const float* src = agg + (tilebase + rr) * 64 + cc;
    unsigned int* dstp = A + (16 * w + rr) * ASTR + cc;
#pragma unroll
    for (int j4 = 0; j4 < 4; ++j4) {
      float4 v = *(const float4*)(src + 4 * j4);
      uint4v pv;
      pv[0] = bsplit(v.x); pv[1] = bsplit(v.y); pv[2] = bsplit(v.z); pv[3] = bsplit(v.w);
      *(uint4v*)(dstp + 4 * j4) = pv;
    }
  }
  __syncthreads();

  const unsigned int* Arow = A + (16 * w + c) * ASTR;
  f32x4 z = {0.f, 0.f, 0.f, 0.f};
  f32x4 acc[4] = {z, z, z, z};
  gemm64(Arow, w2, c, q, acc);

  // epilogue: + b2 + x2, LN over n per row, gelu
  float v[4][4];
#pragma unroll
  for (int t = 0; t < 4; ++t)
#pragma unroll
    for (int r = 0; r < 4; ++r)
      v[t][r] = acc[t][r] + vb[t] + x2v[t][r];

  float mean[4], var[4];
#pragma unroll
  for (int r = 0; r < 4; ++r) {
    float s = v[0][r] + v[1][r] + v[2][r] + v[3][r];
    s += __shfl_xor(s, 1, 64); s += __shfl_xor(s, 2, 64);
    s += __shfl_xor(s, 4, 64); s += __shfl_xor(s, 8, 64);
    mean[r] = s * (1.0f / 64.0f);
  }
#pragma unroll
  for (int r = 0; r < 4; ++r) {
    float s = 0.f;
#pragma unroll
    for (int t = 0; t < 4; ++t) { float d = v[t][r] - mean[r]; s += d * d; }
    s += __shfl_xor(s, 1, 64); s += __shfl_xor(s, 2, 64);
    s += __shfl_xor(s, 4, 64); s += __shfl_xor(s, 8, 64);
    var[r] = s * (1.0f / 64.0f);
  }
#pragma unroll
  for (int t = 0; t < 4; ++t)
#pragma unroll
    for (int r = 0; r < 4; ++r) {
      float d = v[t][r] - mean[r];
      float h = d * rsqrtf(var[r] + 1e-5f) * lg[t] + lb[t];
      v[t][r] = gelu_exact(h);
    }

  // transpose h into LDS (wave-private rows; in-wave LDS ordering by compiler)
#pragma unroll
  for (int t = 0; t < 4; ++t)
#pragma unroll
    for (int r = 0; r < 4; ++r)
      A[(16 * w + 4 * q + r) * ASTR + 16 * t + c] = bsplit(v[t][r]);

  f32x4 acch[4] = {z, z, z, z};
  gemm64(Arow, nw1, c, q, acch);
  store_d(hl, nb1, tilebase, c, q, acch);

  f32x4 accx[4] = {z, z, z, z};
  gemm64(Arow, nwc, c, q, accx);
  store_d(x2, nwcb, tilebase, c, q, accx);
}

// ---------------------------------------------------------------------------
// post (layer 2) + head: h = LN(agg@W2.T + b2 + x2);
// t = gelu(h@fc1.T + fc1b); out = t@fc2.T + fc2b
// ---------------------------------------------------------------------------
__global__ __launch_bounds__(256) void k_post_last(
    const float* __restrict__ agg,
    const float* __restrict__ w2, const float* __restrict__ b2,
    const float* __restrict__ lng, const float* __restrict__ lnb,
    const float* __restrict__ x2,
    const float* __restrict__ fc1w, const float* __restrict__ fc1b,
    const float* __restrict__ fw2, const float* __restrict__ fb2,
    float* __restrict__ out)
{
  __shared__ unsigned int A[64 * ASTR];
  const int tid = threadIdx.x, lane = tid & 63, w = tid >> 6;
  const int tilebase = blockIdx.x * 64 + w * 16;
  const int c = lane & 15, q = lane >> 4;

  float x2v[4][4], lg[4], lb[4], vb[4];
#pragma unroll
  for (int t = 0; t < 4; ++t) {
    int n = 16 * t + c;
    lg[t] = lng[n]; lb[t] = lnb[n]; vb[t] = b2[n];
#pragma unroll
    for (int r = 0; r < 4; ++r)
      x2v[t][r] = x2[(tilebase + 4 * q + r) * 64 + n];
  }

  {
    int rr = lane >> 2, cc = (lane & 3) * 16;
    const float* src = agg + (tilebase + rr) * 64 + cc;
    unsigned int* dstp = A + (16 * w + rr) * ASTR + cc;
#pragma unroll
    for (int j4 = 0; j4 < 4; ++j4) {
      float4 v = *(const float4*)(src + 4 * j4);
      uint4v pv;
      pv[0] = bsplit(v.x); pv[1] = bsplit(v.y); pv[2] = bsplit(v.z); pv[3] = bsplit(v.w);
      *(uint4v*)(dstp + 4 * j4) = pv;
    }
  }
  __syncthreads();

  const unsigned int* Arow = A + (16 * w + c) * ASTR;
  f32x4 z = {0.f, 0.f, 0.f, 0.f};
  f32x4 acc[4] = {z, z, z, z};
  gemm64(Arow, w2, c, q, acc);

  float v[4][4];
#pragma unroll
  for (int t = 0; t < 4; ++t)
#pragma unroll
    for (int r = 0; r < 4; ++r)
      v[t][r] = acc[t][r] + vb[t] + x2v[t][r];

  float mean[4], var[4];
#pragma unroll
  for (int r = 0; r < 4; ++r) {
    float s = v[0][r] + v[1][r] + v[2][r] + v[3][r];
    s += __shfl_xor(s, 1, 64); s += __shfl_xor(s, 2, 64);
    s += __shfl_xor(s, 4, 64); s += __shfl_xor(s, 8, 64);
    mean[r] = s * (1.0f / 64.0f);
  }
#pragma unroll
  for (int r = 0; r < 4; ++r) {
    float s = 0.f;
#pragma unroll
    for (int t = 0; t < 4; ++t) { float d = v[t][r] - mean[r]; s += d * d; }
    s += __shfl_xor(s, 1, 64); s += __shfl_xor(s, 2, 64);
    s += __shfl_xor(s, 4, 64); s += __shfl_xor(s, 8, 64);
    var[r] = s * (1.0f / 64.0f);
  }
#pragma unroll
  for (int t = 0; t < 4; ++t)
#pragma unroll
    for (int r = 0; r < 4; ++r) {
      float d = v[t][r] - mean[r];
      v[t][r] = d * rsqrtf(var[r] + 1e-5f) * lg[t] + lb[t];   // no gelu on last h
    }

  // transpose h into LDS
#pragma unroll
  for (int t = 0; t < 4; ++t)
#pragma unroll
    for (int r = 0; r < 4; ++r)
      A[(16 * w + 4 * q + r) * ASTR + 16 * t + c] = bsplit(v[t][r]);

  // head: t = gelu(h@fc1.T + fc1b); out = sum_n t*fc2w[n] + fc2b
  Frag a0 = load_afrag(Arow + 8 * q);
  Frag a1 = load_afrag(Arow + 32 + 8 * q);
  float p[4] = {0.f, 0.f, 0.f, 0.f};
#pragma unroll
  for (int t8 = 0; t8 < 8; ++t8) {
    Frag b0 = load_bfrag(fc1w + (16 * t8 + c) * 64 + 8 * q);
    Frag b1 = load_bfrag(fc1w + (16 * t8 + c) * 64 + 32 + 8 * q);
    f32x4 a = z;
    a = mfma3(a0, b0, a);
    a = mfma3(a1, b1, a);
    float fbv = fc1b[16 * t8 + c];
    float fwv = fw2[16 * t8 + c];
#pragma unroll
    for (int r = 0; r < 4; ++r) p[r] += gelu_exact(a[r] + fbv) * fwv;
  }
#pragma unroll
  for (int r = 0; r < 4; ++r) {
    float s = p[r];
    s += __shfl_xor(s, 1, 64); s += __shfl_xor(s, 2, 64);
    s += __shfl_xor(s, 4, 64); s += __shfl_xor(s, 8, 64);
    p[r] = s;
  }
  if (c == 0) {
    float bb = fb2[0];
#pragma unroll
    for (int r = 0; r < 4; ++r) out[tilebase + 4 * q + r] = p[r] + bb;
  }
}

// ---------------------------------------------------------------------------
extern "C" void kernel_launch(void* const* d_in, const int* in_sizes, int n_in,
                              void* d_out, int out_size, void* d_ws, size_t ws_size,
                              hipStream_t stream) {
  const float* x     = (const float*)d_in[0];
  const int* ei      = (const int*)d_in[1];
  const float* fc0_w = (const float*)d_in[2];
  const float* fc0_b = (const float*)d_in[3];
  const float* ln0_g = (const float*)d_in[4];
  const float* ln0_b = (const float*)d_in[5];
  const float* gg_fc1_w = (const float*)d_in[6];
  const float* gg_fc1_b = (const float*)d_in[7];
  const float* gg_fc2_w = (const float*)d_in[8];
  const float* gg_fc2_b = (const float*)d_in[9];
  const float* gg_weight = (const float*)d_in[10];
  const float* gg_freq   = (const float*)d_in[11];
  const float* wc_w = (const float*)d_in[12];
  const float* wc_b = (const float*)d_in[13];
  const float* ln_g = (const float*)d_in[14];
  const float* ln_b = (const float*)d_in[15];
  const float* fc1_w = (const float*)d_in[16];
  const float* fc1_b = (const float*)d_in[17];
  const float* fc2_w = (const float*)d_in[18];
  const float* fc2_b = (const float*)d_in[19];

  char* ws = (char*)d_ws;
  size_t off = 0;
  auto alloc = [&](size_t bytes) -> void* {
    void* p = ws + off;
    off = (off + bytes + 255) & ~(size_t)255;
    return p;
  };
  float2* grid2   = (float2*)alloc((size_t)M_NODES * 8);
  float*  gwf     = (float*)alloc((size_t)M_NODES * 4);
  float*  hl      = (float*)alloc((size_t)M_NODES * 64 * 4);
  float*  agg     = (float*)alloc((size_t)M_NODES * 64 * 4);
  float*  x2      = (float*)alloc((size_t)M_NODES * 64 * 4);
  int*    cnt     = (int*)alloc((size_t)M_NODES * 4);
  int*    cursor  = (int*)alloc((size_t)M_NODES * 4);
  int*    row_st  = (int*)alloc((size_t)(M_NODES + 1) * 4);
  float4* rec     = (float4*)alloc((size_t)E_EDGES * 16);
  (void)ws_size; (void)in_sizes; (void)n_in; (void)out_size;

  hipMemsetAsync(cnt, 0, (size_t)M_NODES * 4, stream);

  k_init<<<M_NODES / 64, 256, 0, stream>>>(x, fc0_w, fc0_b, ln0_g, ln0_b,
                                           gg_fc1_w, gg_fc1_b, wc_w, wc_b,
                                           grid2, gwf, hl, x2);
  k_count<<<E_EDGES / 256, 256, 0, stream>>>(ei, cnt);
  k_scan<<<1, 1024, 0, stream>>>(cnt, row_st, cursor);
  k_scatter<<<E_EDGES / 256, 256, 0, stream>>>(ei, grid2, gwf, cursor, rec);

  for (int l = 0; l < 3; ++l) {
    k_agg<<<M_NODES / 4, 256, 0, stream>>>(rec, row_st, hl,
                                           gg_weight + l * 64, gg_freq + l * 128, agg);
    if (l < 2) {
      k_post_mid<<<M_NODES / 64, 256, 0, stream>>>(
          agg,
          gg_fc2_w + l * 4096, gg_fc2_b + l * 64,
          ln_g + l * 64, ln_b + l * 64,
          gg_fc1_w + (l + 1) * 4096, gg_fc1_b + (l + 1) * 64,
          wc_w + (l + 1) * 4096, wc_b + (l + 1) * 64,
          hl, x2);
    } else {
      k_post_last<<<M_NODES / 64, 256, 0, stream>>>(
          agg,
          gg_fc2_w + l * 4096, gg_fc2_b + l * 64,
          ln_g + l * 64, ln_b + l * 64,
          x2,
          fc1_w, fc1_b, fc2_w, fc2_b,
          (float*)d_out);
    }
  }
}

// Round 4
// 310.319 us; speedup vs baseline: 1.6051x; 1.1819x over previous
//
#include <hip/hip_runtime.h>
#include <hip/hip_bf16.h>

#define M_NODES 16384
#define E_EDGES 524288
#define ASTR 68   // uint stride of LDS A rows: 2-way bank alias only (free), 16B-aligned rows

typedef short short8 __attribute__((ext_vector_type(8)));
typedef float f32x4 __attribute__((ext_vector_type(4)));
typedef unsigned int uint4v __attribute__((ext_vector_type(4)));

static __device__ __forceinline__ float wredsum(float v) {
#pragma unroll
  for (int o = 32; o > 0; o >>= 1) v += __shfl_xor(v, o, 64);
  return v;
}

static __device__ __forceinline__ float gelu_exact(float x) {
  return 0.5f * x * (1.0f + erff(x * 0.70710678118654752440f));
}

// split fp32 -> (bf16 hi | bf16 lo) packed in one uint (hi in low 16, lo in high 16)
static __device__ __forceinline__ unsigned int bsplit(float x) {
  unsigned int u = __float_as_uint(x);
  unsigned int hb = (u + 0x7FFFu + ((u >> 16) & 1u)) >> 16;   // RNE bf16 of x
  float hf = __uint_as_float(hb << 16);
  float r = x - hf;
  unsigned int v = __float_as_uint(r);
  unsigned int lb = (v + 0x7FFFu + ((v >> 16) & 1u)) >> 16;   // RNE bf16 of residual
  return (hb & 0xFFFFu) | (lb << 16);
}

struct Frag { short8 hi, lo; };

// 8 consecutive packed uints (16B aligned) -> hi/lo bf16 fragments
static __device__ __forceinline__ Frag load_afrag(const unsigned int* a) {
  uint4v u0 = *(const uint4v*)a;
  uint4v u1 = *(const uint4v*)(a + 4);
  Frag f;
#pragma unroll
  for (int j = 0; j < 4; ++j) {
    f.hi[j]     = (short)(u0[j] & 0xFFFFu);
    f.lo[j]     = (short)(u0[j] >> 16);
    f.hi[j + 4] = (short)(u1[j] & 0xFFFFu);
    f.lo[j + 4] = (short)(u1[j] >> 16);
  }
  return f;
}

// 8 consecutive fp32 from global (32B aligned) -> hi/lo fragments
static __device__ __forceinline__ Frag load_bfrag(const float* __restrict__ w) {
  float4 w0 = *(const float4*)w;
  float4 w1 = *(const float4*)(w + 4);
  float v[8] = {w0.x, w0.y, w0.z, w0.w, w1.x, w1.y, w1.z, w1.w};
  Frag f;
#pragma unroll
  for (int j = 0; j < 8; ++j) {
    unsigned int p = bsplit(v[j]);
    f.hi[j] = (short)(p & 0xFFFFu);
    f.lo[j] = (short)(p >> 16);
  }
  return f;
}

static __device__ __forceinline__ f32x4 mfma3(const Frag& a, const Frag& b, f32x4 c) {
  c = __builtin_amdgcn_mfma_f32_16x16x32_bf16(a.hi, b.hi, c, 0, 0, 0);
  c = __builtin_amdgcn_mfma_f32_16x16x32_bf16(a.lo, b.hi, c, 0, 0, 0);
  c = __builtin_amdgcn_mfma_f32_16x16x32_bf16(a.hi, b.lo, c, 0, 0, 0);
  return c;
}

// D[m][n] = sum_k A[m][k] * W[n][k] for one wave's 16-node tile, 64 outputs.
static __device__ __forceinline__ void gemm64(const unsigned int* Arow,
                                              const float* __restrict__ W,
                                              int c, int q, f32x4 acc[4]) {
  Frag a0 = load_afrag(Arow + 8 * q);        // k-step 0: k = 8q + j
  Frag a1 = load_afrag(Arow + 32 + 8 * q);   // k-step 1: k = 32 + 8q + j
#pragma unroll
  for (int t = 0; t < 4; ++t) {
    Frag b0 = load_bfrag(W + (16 * t + c) * 64 + 8 * q);
    Frag b1 = load_bfrag(W + (16 * t + c) * 64 + 32 + 8 * q);
    acc[t] = mfma3(a0, b0, acc[t]);
    acc[t] = mfma3(a1, b1, acc[t]);
  }
}

// store D + bias[n] to O[node*64 + n]; D layout: col = 16t+c, row = 4q+r
static __device__ __forceinline__ void store_d(float* __restrict__ O,
                                               const float* __restrict__ bias,
                                               int tilebase, int c, int q,
                                               const f32x4 acc[4]) {
#pragma unroll
  for (int t = 0; t < 4; ++t) {
    float bn = bias[16 * t + c];
#pragma unroll
    for (int r = 0; r < 4; ++r)
      O[(tilebase + 4 * q + r) * 64 + 16 * t + c] = acc[t][r] + bn;
  }
}

// ---------------------------------------------------------------------------
// k_init: h0 = LN(feat@fc0.T+b) per-lane; then MFMA: hl0 = h0@W1[0].T+b1,
// x2_0 = h0@Wc[0].T+wcb. Block = 4 waves = 64 nodes.
// ---------------------------------------------------------------------------
__global__ __launch_bounds__(256) void k_init(
    const float* __restrict__ x,
    const float* __restrict__ fc0_w, const float* __restrict__ fc0_b,
    const float* __restrict__ ln0_g, const float* __restrict__ ln0_b,
    const float* __restrict__ w1, const float* __restrict__ b1,
    const float* __restrict__ wc, const float* __restrict__ wcb,
    float2* __restrict__ grid2, float* __restrict__ gwf,
    float* __restrict__ hl, float* __restrict__ x2)
{
  __shared__ unsigned int A[64 * ASTR];
  const int tid = threadIdx.x;
  const int lane = tid & 63;
  const int w = tid >> 6;
  const int tilebase = blockIdx.x * 64 + w * 16;

  float fw0 = fc0_w[lane * 4 + 0], fw1 = fc0_w[lane * 4 + 1];
  float fw2v = fc0_w[lane * 4 + 2], fw3 = fc0_w[lane * 4 + 3];
  float fb = fc0_b[lane], g0 = ln0_g[lane], bb0 = ln0_b[lane];

  for (int i = 0; i < 16; ++i) {
    int node = tilebase + i;
    float xv0 = x[node * 5 + 0], xv1 = x[node * 5 + 1], xv2 = x[node * 5 + 2];
    float xv3 = x[node * 5 + 3], xv4 = x[node * 5 + 4];
    float acc = fb + xv0 * fw0 + xv1 * fw1 + xv2 * fw2v + xv3 * fw3;
    float mean = wredsum(acc) * (1.0f / 64.0f);
    float d = acc - mean;
    float var = wredsum(d * d) * (1.0f / 64.0f);
    float hv = d * rsqrtf(var + 1e-5f) * g0 + bb0;
    A[(w * 16 + i) * ASTR + lane] = bsplit(hv);
    if (lane == 0) { grid2[node] = make_float2(xv2, xv3); gwf[node] = xv4; }
  }
  __syncthreads();

  const int c = lane & 15, q = lane >> 4;
  const unsigned int* Arow = A + (w * 16 + c) * ASTR;

  f32x4 z = {0.f, 0.f, 0.f, 0.f};
  f32x4 acc1[4] = {z, z, z, z};
  gemm64(Arow, w1, c, q, acc1);
  store_d(hl, b1, tilebase, c, q, acc1);

  f32x4 acc2[4] = {z, z, z, z};
  gemm64(Arow, wc, c, q, acc2);
  store_d(x2, wcb, tilebase, c, q, acc2);
}

// ---------------------------------------------------------------------------
// counting sort of edges by dst
// ---------------------------------------------------------------------------
__global__ __launch_bounds__(256) void k_count(const int* __restrict__ ei, int* __restrict__ cnt)
{
  int e = blockIdx.x * 256 + threadIdx.x;
  if (e < E_EDGES) atomicAdd(&cnt[ei[E_EDGES + e]], 1);
}

__global__ __launch_bounds__(1024) void k_scan(const int* __restrict__ cnt,
                                               int* __restrict__ row_start,
                                               int* __restrict__ cursor)
{
  const int PER = M_NODES / 1024;   // 16
  const int t = threadIdx.x;
  const int base = t * PER;
  int local[PER];
  int s = 0;
#pragma unroll
  for (int k = 0; k < PER; ++k) { local[k] = cnt[base + k]; s += local[k]; }

  __shared__ int part[1024];
  part[t] = s;
  __syncthreads();
  for (int off = 1; off < 1024; off <<= 1) {
    int v = (t >= off) ? part[t - off] : 0;
    __syncthreads();
    part[t] += v;
    __syncthreads();
  }
  int run = part[t] - s;
#pragma unroll
  for (int k = 0; k < PER; ++k) {
    row_start[base + k] = run;
    cursor[base + k] = run;
    run += local[k];
  }
  if (t == 1023) row_start[M_NODES] = run;
}

__global__ __launch_bounds__(256) void k_scatter(
    const int* __restrict__ ei, const float2* __restrict__ grid2,
    const float* __restrict__ gwf, int* __restrict__ cursor,
    float4* __restrict__ rec)
{
  int e = blockIdx.x * 256 + threadIdx.x;
  if (e < E_EDGES) {
    int s = ei[e];
    int dd = ei[E_EDGES + e];
    int pos = atomicAdd(&cursor[dd], 1);
    float2 gs = grid2[s], gd = grid2[dd];
    rec[pos] = make_float4(gs.x - gd.x, gs.y - gd.y, gwf[s], __int_as_float(s));
  }
}

// ---------------------------------------------------------------------------
// edge aggregation: hardware transcendentals.
//   gauss = exp2( -w*log2e*dist2 + log2(w/pi) )       (1 fma + 1 v_exp)
//   four  = v_sin( fract( vx*f0/2pi + vy*f1/2pi ) )   (fma+mul+fract+sin)
// 1-deep software pipeline on rec -> hl dependent loads.
// ---------------------------------------------------------------------------
__global__ __launch_bounds__(256) void k_agg(
    const float4* __restrict__ rec, const int* __restrict__ row_start,
    const float* __restrict__ hl,
    const float* __restrict__ gw, const float* __restrict__ freq,
    float* __restrict__ agg)
{
  const int lane = threadIdx.x & 63;
  const int node = blockIdx.x * 4 + (threadIdx.x >> 6);

  const float w = gw[lane];                       // in [0.5, 1.5]
  const float nwl2 = -w * 1.44269504088896340736f;        // -w*log2(e)
  const float lc = log2f(w * 0.31830988618379067154f);    // log2(w/pi)
  const float f0s = freq[lane] * 0.15915494309189533577f; // f0/(2pi)
  const float f1s = freq[64 + lane] * 0.15915494309189533577f;

  const int beg = row_start[node];
  const int end = row_start[node + 1];
  float acc = 0.0f;

  int i = beg;
  if (i < end) {
    float4 r = rec[i];
    float hlv = hl[__float_as_int(r.w) * 64 + lane];
    for (++i; i < end; ++i) {
      float4 rn = rec[i];                                     // next edge rec
      float hn = hl[__float_as_int(rn.w) * 64 + lane];        // next edge gather
      float dist2 = r.x * r.x + r.y * r.y;
      float gs = __builtin_amdgcn_exp2f(__builtin_fmaf(nwl2, dist2, lc));
      float rev = __builtin_fmaf(r.x, f0s, r.y * f1s);
      float fo = __builtin_amdgcn_sinf(__builtin_amdgcn_fractf(rev));
      acc = __builtin_fmaf(gs * fo * hlv, r.z, acc);
      r = rn; hlv = hn;
    }
    float dist2 = r.x * r.x + r.y * r.y;
    float gs = __builtin_amdgcn_exp2f(__builtin_fmaf(nwl2, dist2, lc));
    float rev = __builtin_fmaf(r.x, f0s, r.y * f1s);
    float fo = __builtin_amdgcn_sinf(__builtin_amdgcn_fractf(rev));
    acc = __builtin_fmaf(gs * fo * hlv, r.z, acc);
  }
  agg[node * 64 + lane] = acc;
}

// ---------------------------------------------------------------------------
// post (layers 0,1): S = agg@W2.T + b2 + x2 ; h = gelu(LN(S));
// then hl = h@W1next.T + b1next ; x2 = h@Wcnext.T + wcbnext
// ---------------------------------------------------------------------------
__global__ __launch_bounds__(256) void k_post_mid(
    const float* __restrict__ agg,
    const float* __restrict__ w2, const float* __restrict__ b2,
    const float* __restrict__ lng, const float* __restrict__ lnb,
    const float* __restrict__ nw1, const float* __restrict__ nb1,
    const float* __restrict__ nwc, const float* __restrict__ nwcb,
    float* __restrict__ hl, float* __restrict__ x2)
{
  __shared__ unsigned int A[64 * ASTR];
  const int tid = threadIdx.x, lane = tid & 63, w = tid >> 6;
  const int tilebase = blockIdx.x * 64 + w * 16;
  const int c = lane & 15, q = lane >> 4;

  float x2v[4][4], lg[4], lb[4], vb[4];
#pragma unroll
  for (int t = 0; t < 4; ++t) {
    int n = 16 * t + c;
    lg[t] = lng[n]; lb[t] = lnb[n]; vb[t] = b2[n];
#pragma unroll
    for (int r = 0; r < 4; ++r)
      x2v[t][r] = x2[(tilebase + 4 * q + r) * 64 + n];
  }

  {
    int rr = lane >> 2, cc = (lane & 3) * 16;
    const float* src = agg + (tilebase + rr) * 64 + cc;
    unsigned int* dstp = A + (16 * w + rr) * ASTR + cc;
#pragma unroll
    for (int j4 = 0; j4 < 4; ++j4) {
      float4 v = *(const float4*)(src + 4 * j4);
      uint4v pv;
      pv[0] = bsplit(v.x); pv[1] = bsplit(v.y); pv[2] = bsplit(v.z); pv[3] = bsplit(v.w);
      *(uint4v*)(dstp + 4 * j4) = pv;
    }
  }
  __syncthreads();

  const unsigned int* Arow = A + (16 * w + c) * ASTR;
  f32x4 z = {0.f, 0.f, 0.f, 0.f};
  f32x4 acc[4] = {z, z, z, z};
  gemm64(Arow, w2, c, q, acc);

  float v[4][4];
#pragma unroll
  for (int t = 0; t < 4; ++t)
#pragma unroll
    for (int r = 0; r < 4; ++r)
      v[t][r] = acc[t][r] + vb[t] + x2v[t][r];

  float mean[4], var[4];
#pragma unroll
  for (int r = 0; r < 4; ++r) {
    float s = v[0][r] + v[1][r] + v[2][r] + v[3][r];
    s += __shfl_xor(s, 1, 64); s += __shfl_xor(s, 2, 64);
    s += __shfl_xor(s, 4, 64); s += __shfl_xor(s, 8, 64);
    mean[r] = s * (1.0f / 64.0f);
  }
#pragma unroll
  for (int r = 0; r < 4; ++r) {
    float s = 0.f;
#pragma unroll
    for (int t = 0; t < 4; ++t) { float d = v[t][r] - mean[r]; s += d * d; }
    s += __shfl_xor(s, 1, 64); s += __shfl_xor(s, 2, 64);
    s += __shfl_xor(s, 4, 64); s += __shfl_xor(s, 8, 64);
    var[r] = s * (1.0f / 64.0f);
  }
#pragma unroll
  for (int t = 0; t < 4; ++t)
#pragma unroll
    for (int r = 0; r < 4; ++r) {
      float d = v[t][r] - mean[r];
      float h = d * rsqrtf(var[r] + 1e-5f) * lg[t] + lb[t];
      v[t][r] = gelu_exact(h);
    }

#pragma unroll
  for (int t = 0; t < 4; ++t)
#pragma unroll
    for (int r = 0; r < 4; ++r)
      A[(16 * w + 4 * q + r) * ASTR + 16 * t + c] = bsplit(v[t][r]);

  f32x4 acch[4] = {z, z, z, z};
  gemm64(Arow, nw1, c, q, acch);
  store_d(hl, nb1, tilebase, c, q, acch);

  f32x4 accx[4] = {z, z, z, z};
  gemm64(Arow, nwc, c, q, accx);
  store_d(x2, nwcb, tilebase, c, q, accx);
}

// ---------------------------------------------------------------------------
// post (layer 2) + head: h = LN(agg@W2.T + b2 + x2);
// t = gelu(h@fc1.T + fc1b); out = t@fc2.T + fc2b
// ---------------------------------------------------------------------------
__global__ __launch_bounds__(256) void k_post_last(
    const float* __restrict__ agg,
    const float* __restrict__ w2, const float* __restrict__ b2,
    const float* __restrict__ lng, const float* __restrict__ lnb,
    const float* __restrict__ x2,
    const float* __restrict__ fc1w, const float* __restrict__ fc1b,
    const float* __restrict__ fw2, const float* __restrict__ fb2,
    float* __restrict__ out)
{
  __shared__ unsigned int A[64 * ASTR];
  const int tid = threadIdx.x, lane = tid & 63, w = tid >> 6;
  const int tilebase = blockIdx.x * 64 + w * 16;
  const int c = lane & 15, q = lane >> 4;

  float x2v[4][4], lg[4], lb[4], vb[4];
#pragma unroll
  for (int t = 0; t < 4; ++t) {
    int n = 16 * t + c;
    lg[t] = lng[n]; lb[t] = lnb[n]; vb[t] = b2[n];
#pragma unroll
    for (int r = 0; r < 4; ++r)
      x2v[t][r] = x2[(tilebase + 4 * q + r) * 64 + n];
  }

  {
    int rr = lane >> 2, cc = (lane & 3) * 16;
    const float* src = agg + (tilebase + rr) * 64 + cc;
    unsigned int* dstp = A + (16 * w + rr) * ASTR + cc;
#pragma unroll
    for (int j4 = 0; j4 < 4; ++j4) {
      float4 v = *(const float4*)(src + 4 * j4);
      uint4v pv;
      pv[0] = bsplit(v.x); pv[1] = bsplit(v.y); pv[2] = bsplit(v.z); pv[3] = bsplit(v.w);
      *(uint4v*)(dstp + 4 * j4) = pv;
    }
  }
  __syncthreads();

  const unsigned int* Arow = A + (16 * w + c) * ASTR;
  f32x4 z = {0.f, 0.f, 0.f, 0.f};
  f32x4 acc[4] = {z, z, z, z};
  gemm64(Arow, w2, c, q, acc);

  float v[4][4];
#pragma unroll
  for (int t = 0; t < 4; ++t)
#pragma unroll
    for (int r = 0; r < 4; ++r)
      v[t][r] = acc[t][r] + vb[t] + x2v[t][r];

  float mean[4], var[4];
#pragma unroll
  for (int r = 0; r < 4; ++r) {
    float s = v[0][r] + v[1][r] + v[2][r] + v[3][r];
    s += __shfl_xor(s, 1, 64); s += __shfl_xor(s, 2, 64);
    s += __shfl_xor(s, 4, 64); s += __shfl_xor(s, 8, 64);
    mean[r] = s * (1.0f / 64.0f);
  }
#pragma unroll
  for (int r = 0; r < 4; ++r) {
    float s = 0.f;
#pragma unroll
    for (int t = 0; t < 4; ++t) { float d = v[t][r] - mean[r]; s += d * d; }
    s += __shfl_xor(s, 1, 64); s += __shfl_xor(s, 2, 64);
    s += __shfl_xor(s, 4, 64); s += __shfl_xor(s, 8, 64);
    var[r] = s * (1.0f / 64.0f);
  }
#pragma unroll
  for (int t = 0; t < 4; ++t)
#pragma unroll
    for (int r = 0; r < 4; ++r) {
      float d = v[t][r] - mean[r];
      v[t][r] = d * rsqrtf(var[r] + 1e-5f) * lg[t] + lb[t];   // no gelu on last h
    }

#pragma unroll
  for (int t = 0; t < 4; ++t)
#pragma unroll
    for (int r = 0; r < 4; ++r)
      A[(16 * w + 4 * q + r) * ASTR + 16 * t + c] = bsplit(v[t][r]);

  Frag a0 = load_afrag(Arow + 8 * q);
  Frag a1 = load_afrag(Arow + 32 + 8 * q);
  float p[4] = {0.f, 0.f, 0.f, 0.f};
#pragma unroll
  for (int t8 = 0; t8 < 8; ++t8) {
    Frag b0 = load_bfrag(fc1w + (16 * t8 + c) * 64 + 8 * q);
    Frag b1 = load_bfrag(fc1w + (16 * t8 + c) * 64 + 32 + 8 * q);
    f32x4 a = z;
    a = mfma3(a0, b0, a);
    a = mfma3(a1, b1, a);
    float fbv = fc1b[16 * t8 + c];
    float fwv = fw2[16 * t8 + c];
#pragma unroll
    for (int r = 0; r < 4; ++r) p[r] += gelu_exact(a[r] + fbv) * fwv;
  }
#pragma unroll
  for (int r = 0; r < 4; ++r) {
    float s = p[r];
    s += __shfl_xor(s, 1, 64); s += __shfl_xor(s, 2, 64);
    s += __shfl_xor(s, 4, 64); s += __shfl_xor(s, 8, 64);
    p[r] = s;
  }
  if (c == 0) {
    float bb = fb2[0];
#pragma unroll
    for (int r = 0; r < 4; ++r) out[tilebase + 4 * q + r] = p[r] + bb;
  }
}

// ---------------------------------------------------------------------------
extern "C" void kernel_launch(void* const* d_in, const int* in_sizes, int n_in,
                              void* d_out, int out_size, void* d_ws, size_t ws_size,
                              hipStream_t stream) {
  const float* x     = (const float*)d_in[0];
  const int* ei      = (const int*)d_in[1];
  const float* fc0_w = (const float*)d_in[2];
  const float* fc0_b = (const float*)d_in[3];
  const float* ln0_g = (const float*)d_in[4];
  const float* ln0_b = (const float*)d_in[5];
  const float* gg_fc1_w = (const float*)d_in[6];
  const float* gg_fc1_b = (const float*)d_in[7];
  const float* gg_fc2_w = (const float*)d_in[8];
  const float* gg_fc2_b = (const float*)d_in[9];
  const float* gg_weight = (const float*)d_in[10];
  const float* gg_freq   = (const float*)d_in[11];
  const float* wc_w = (const float*)d_in[12];
  const float* wc_b = (const float*)d_in[13];
  const float* ln_g = (const float*)d_in[14];
  const float* ln_b = (const float*)d_in[15];
  const float* fc1_w = (const float*)d_in[16];
  const float* fc1_b = (const float*)d_in[17];
  const float* fc2_w = (const float*)d_in[18];
  const float* fc2_b = (const float*)d_in[19];

  char* ws = (char*)d_ws;
  size_t off = 0;
  auto alloc = [&](size_t bytes) -> void* {
    void* p = ws + off;
    off = (off + bytes + 255) & ~(size_t)255;
    return p;
  };
  float2* grid2   = (float2*)alloc((size_t)M_NODES * 8);
  float*  gwf     = (float*)alloc((size_t)M_NODES * 4);
  float*  hl      = (float*)alloc((size_t)M_NODES * 64 * 4);
  float*  agg     = (float*)alloc((size_t)M_NODES * 64 * 4);
  float*  x2      = (float*)alloc((size_t)M_NODES * 64 * 4);
  int*    cnt     = (int*)alloc((size_t)M_NODES * 4);
  int*    cursor  = (int*)alloc((size_t)M_NODES * 4);
  int*    row_st  = (int*)alloc((size_t)(M_NODES + 1) * 4);
  float4* rec     = (float4*)alloc((size_t)E_EDGES * 16);
  (void)ws_size; (void)in_sizes; (void)n_in; (void)out_size;

  hipMemsetAsync(cnt, 0, (size_t)M_NODES * 4, stream);

  k_init<<<M_NODES / 64, 256, 0, stream>>>(x, fc0_w, fc0_b, ln0_g, ln0_b,
                                           gg_fc1_w, gg_fc1_b, wc_w, wc_b,
                                           grid2, gwf, hl, x2);
  k_count<<<E_EDGES / 256, 256, 0, stream>>>(ei, cnt);
  k_scan<<<1, 1024, 0, stream>>>(cnt, row_st, cursor);
  k_scatter<<<E_EDGES / 256, 256, 0, stream>>>(ei, grid2, gwf, cursor, rec);

  for (int l = 0; l < 3; ++l) {
    k_agg<<<M_NODES / 4, 256, 0, stream>>>(rec, row_st, hl,
                                           gg_weight + l * 64, gg_freq + l * 128, agg);
    if (l < 2) {
      k_post_mid<<<M_NODES / 64, 256, 0, stream>>>(
          agg,
          gg_fc2_w + l * 4096, gg_fc2_b + l * 64,
          ln_g + l * 64, ln_b + l * 64,
          gg_fc1_w + (l + 1) * 4096, gg_fc1_b + (l + 1) * 64,
          wc_w + (l + 1) * 4096, wc_b + (l + 1) * 64,
          hl, x2);
    } else {
      k_post_last<<<M_NODES / 64, 256, 0, stream>>>(
          agg,
          gg_fc2_w + l * 4096, gg_fc2_b + l * 64,
          ln_g + l * 64, ln_b + l * 64,
          x2,
          fc1_w, fc1_b, fc2_w, fc2_b,
          (float*)d_out);
    }
  }
}

// Round 5
// 287.952 us; speedup vs baseline: 1.7298x; 1.0777x over previous
//
#include <hip/hip_runtime.h>
#include <hip/hip_bf16.h>

#define M_NODES 16384
#define E_EDGES 524288
#define ASTR 68   // uint stride of LDS A rows: 2-way bank alias only (free), 16B-aligned rows

typedef short short8 __attribute__((ext_vector_type(8)));
typedef float f32x4 __attribute__((ext_vector_type(4)));
typedef unsigned int uint4v __attribute__((ext_vector_type(4)));

static __device__ __forceinline__ float wredsum(float v) {
#pragma unroll
  for (int o = 32; o > 0; o >>= 1) v += __shfl_xor(v, o, 64);
  return v;
}

static __device__ __forceinline__ float gelu_exact(float x) {
  return 0.5f * x * (1.0f + erff(x * 0.70710678118654752440f));
}

// split fp32 -> (bf16 hi | bf16 lo) packed in one uint (hi in low 16, lo in high 16)
static __device__ __forceinline__ unsigned int bsplit(float x) {
  unsigned int u = __float_as_uint(x);
  unsigned int hb = (u + 0x7FFFu + ((u >> 16) & 1u)) >> 16;   // RNE bf16 of x
  float hf = __uint_as_float(hb << 16);
  float r = x - hf;
  unsigned int v = __float_as_uint(r);
  unsigned int lb = (v + 0x7FFFu + ((v >> 16) & 1u)) >> 16;   // RNE bf16 of residual
  return (hb & 0xFFFFu) | (lb << 16);
}

struct Frag { short8 hi, lo; };

// 8 consecutive packed uints (16B aligned) -> hi/lo bf16 fragments
static __device__ __forceinline__ Frag load_afrag(const unsigned int* a) {
  uint4v u0 = *(const uint4v*)a;
  uint4v u1 = *(const uint4v*)(a + 4);
  Frag f;
#pragma unroll
  for (int j = 0; j < 4; ++j) {
    f.hi[j]     = (short)(u0[j] & 0xFFFFu);
    f.lo[j]     = (short)(u0[j] >> 16);
    f.hi[j + 4] = (short)(u1[j] & 0xFFFFu);
    f.lo[j + 4] = (short)(u1[j] >> 16);
  }
  return f;
}

// 8 consecutive fp32 from global (32B aligned) -> hi/lo fragments
static __device__ __forceinline__ Frag load_bfrag(const float* __restrict__ w) {
  float4 w0 = *(const float4*)w;
  float4 w1 = *(const float4*)(w + 4);
  float v[8] = {w0.x, w0.y, w0.z, w0.w, w1.x, w1.y, w1.z, w1.w};
  Frag f;
#pragma unroll
  for (int j = 0; j < 8; ++j) {
    unsigned int p = bsplit(v[j]);
    f.hi[j] = (short)(p & 0xFFFFu);
    f.lo[j] = (short)(p >> 16);
  }
  return f;
}

static __device__ __forceinline__ f32x4 mfma3(const Frag& a, const Frag& b, f32x4 c) {
  c = __builtin_amdgcn_mfma_f32_16x16x32_bf16(a.hi, b.hi, c, 0, 0, 0);
  c = __builtin_amdgcn_mfma_f32_16x16x32_bf16(a.lo, b.hi, c, 0, 0, 0);
  c = __builtin_amdgcn_mfma_f32_16x16x32_bf16(a.hi, b.lo, c, 0, 0, 0);
  return c;
}

// one 16x16 output tile: D[m=0..15][n-tile col c] over K=64 from LDS rows + W rows n
static __device__ __forceinline__ f32x4 gemm16(const unsigned int* __restrict__ A,
                                               const float* __restrict__ W,
                                               int n, int c, int q) {
  Frag a0 = load_afrag(A + c * ASTR + 8 * q);
  Frag a1 = load_afrag(A + c * ASTR + 32 + 8 * q);
  Frag b0 = load_bfrag(W + n * 64 + 8 * q);
  Frag b1 = load_bfrag(W + n * 64 + 32 + 8 * q);
  f32x4 acc = {0.f, 0.f, 0.f, 0.f};
  acc = mfma3(a0, b0, acc);
  acc = mfma3(a1, b1, acc);
  return acc;
}

// ---------------------------------------------------------------------------
// k_init: 16 nodes/block, 4 waves. Wave w: LN for nodes 4w..4w+3 (lane=channel),
// stage h0 to LDS; then n-tile w of hl0 = h0@W1[0].T+b1 and x2_0 = h0@Wc[0].T+wcb.
// ---------------------------------------------------------------------------
__global__ __launch_bounds__(256) void k_init(
    const float* __restrict__ x,
    const float* __restrict__ fc0_w, const float* __restrict__ fc0_b,
    const float* __restrict__ ln0_g, const float* __restrict__ ln0_b,
    const float* __restrict__ w1, const float* __restrict__ b1,
    const float* __restrict__ wc, const float* __restrict__ wcb,
    float2* __restrict__ grid2, float* __restrict__ gwf,
    float* __restrict__ hl, float* __restrict__ x2)
{
  __shared__ unsigned int A[16 * ASTR];
  const int tid = threadIdx.x, lane = tid & 63, w = tid >> 6;
  const int tilebase = blockIdx.x * 16;

  float fw0 = fc0_w[lane * 4 + 0], fw1 = fc0_w[lane * 4 + 1];
  float fw2v = fc0_w[lane * 4 + 2], fw3 = fc0_w[lane * 4 + 3];
  float fb = fc0_b[lane], g0 = ln0_g[lane], bb0 = ln0_b[lane];

#pragma unroll
  for (int i = 0; i < 4; ++i) {
    int node = tilebase + 4 * w + i;
    float xv0 = x[node * 5 + 0], xv1 = x[node * 5 + 1], xv2 = x[node * 5 + 2];
    float xv3 = x[node * 5 + 3], xv4 = x[node * 5 + 4];
    float acc = fb + xv0 * fw0 + xv1 * fw1 + xv2 * fw2v + xv3 * fw3;
    float mean = wredsum(acc) * (1.0f / 64.0f);
    float d = acc - mean;
    float var = wredsum(d * d) * (1.0f / 64.0f);
    float hv = d * rsqrtf(var + 1e-5f) * g0 + bb0;
    A[(4 * w + i) * ASTR + lane] = bsplit(hv);
    if (lane == 0) { grid2[node] = make_float2(xv2, xv3); gwf[node] = xv4; }
  }
  __syncthreads();

  const int c = lane & 15, q = lane >> 4;
  const int n = 16 * w + c;

  f32x4 a1v = gemm16(A, w1, n, c, q);
  float b1v = b1[n];
#pragma unroll
  for (int r = 0; r < 4; ++r)
    hl[(tilebase + 4 * q + r) * 64 + n] = a1v[r] + b1v;

  f32x4 a2v = gemm16(A, wc, n, c, q);
  float wcbv = wcb[n];
#pragma unroll
  for (int r = 0; r < 4; ++r)
    x2[(tilebase + 4 * q + r) * 64 + n] = a2v[r] + wcbv;
}

// ---------------------------------------------------------------------------
// counting sort of edges by dst (unchanged)
// ---------------------------------------------------------------------------
__global__ __launch_bounds__(256) void k_count(const int* __restrict__ ei, int* __restrict__ cnt)
{
  int e = blockIdx.x * 256 + threadIdx.x;
  if (e < E_EDGES) atomicAdd(&cnt[ei[E_EDGES + e]], 1);
}

__global__ __launch_bounds__(1024) void k_scan(const int* __restrict__ cnt,
                                               int* __restrict__ row_start,
                                               int* __restrict__ cursor)
{
  const int PER = M_NODES / 1024;   // 16
  const int t = threadIdx.x;
  const int base = t * PER;
  int local[PER];
  int s = 0;
#pragma unroll
  for (int k = 0; k < PER; ++k) { local[k] = cnt[base + k]; s += local[k]; }

  __shared__ int part[1024];
  part[t] = s;
  __syncthreads();
  for (int off = 1; off < 1024; off <<= 1) {
    int v = (t >= off) ? part[t - off] : 0;
    __syncthreads();
    part[t] += v;
    __syncthreads();
  }
  int run = part[t] - s;
#pragma unroll
  for (int k = 0; k < PER; ++k) {
    row_start[base + k] = run;
    cursor[base + k] = run;
    run += local[k];
  }
  if (t == 1023) row_start[M_NODES] = run;
}

__global__ __launch_bounds__(256) void k_scatter(
    const int* __restrict__ ei, const float2* __restrict__ grid2,
    const float* __restrict__ gwf, int* __restrict__ cursor,
    float4* __restrict__ rec)
{
  int e = blockIdx.x * 256 + threadIdx.x;
  if (e < E_EDGES) {
    int s = ei[e];
    int dd = ei[E_EDGES + e];
    int pos = atomicAdd(&cursor[dd], 1);
    float2 gs = grid2[s], gd = grid2[dd];
    rec[pos] = make_float4(gs.x - gd.x, gs.y - gd.y, gwf[s], __int_as_float(s));
  }
}

// ---------------------------------------------------------------------------
// edge aggregation (unchanged from R4): HW transcendentals + 1-deep pipeline
// ---------------------------------------------------------------------------
__global__ __launch_bounds__(256) void k_agg(
    const float4* __restrict__ rec, const int* __restrict__ row_start,
    const float* __restrict__ hl,
    const float* __restrict__ gw, const float* __restrict__ freq,
    float* __restrict__ agg)
{
  const int lane = threadIdx.x & 63;
  const int node = blockIdx.x * 4 + (threadIdx.x >> 6);

  const float w = gw[lane];                       // in [0.5, 1.5]
  const float nwl2 = -w * 1.44269504088896340736f;        // -w*log2(e)
  const float lc = log2f(w * 0.31830988618379067154f);    // log2(w/pi)
  const float f0s = freq[lane] * 0.15915494309189533577f; // f0/(2pi)
  const float f1s = freq[64 + lane] * 0.15915494309189533577f;

  const int beg = row_start[node];
  const int end = row_start[node + 1];
  float acc = 0.0f;

  int i = beg;
  if (i < end) {
    float4 r = rec[i];
    float hlv = hl[__float_as_int(r.w) * 64 + lane];
    for (++i; i < end; ++i) {
      float4 rn = rec[i];
      float hn = hl[__float_as_int(rn.w) * 64 + lane];
      float dist2 = r.x * r.x + r.y * r.y;
      float gs = __builtin_amdgcn_exp2f(__builtin_fmaf(nwl2, dist2, lc));
      float rev = __builtin_fmaf(r.x, f0s, r.y * f1s);
      float fo = __builtin_amdgcn_sinf(__builtin_amdgcn_fractf(rev));
      acc = __builtin_fmaf(gs * fo * hlv, r.z, acc);
      r = rn; hlv = hn;
    }
    float dist2 = r.x * r.x + r.y * r.y;
    float gs = __builtin_amdgcn_exp2f(__builtin_fmaf(nwl2, dist2, lc));
    float rev = __builtin_fmaf(r.x, f0s, r.y * f1s);
    float fo = __builtin_amdgcn_sinf(__builtin_amdgcn_fractf(rev));
    acc = __builtin_fmaf(gs * fo * hlv, r.z, acc);
  }
  agg[node * 64 + lane] = acc;
}

// ---------------------------------------------------------------------------
// post (layers 0,1): 16 nodes/block, 4 waves; wave w owns n-tile w.
// S = agg@W2.T + b2 + x2; h = gelu(LN(S)); hl = h@W1n.T + b1n; x2 = h@Wcn.T + wcbn
// ---------------------------------------------------------------------------
__global__ __launch_bounds__(256) void k_post_mid(
    const float* __restrict__ agg,
    const float* __restrict__ w2, const float* __restrict__ b2,
    const float* __restrict__ lng, const float* __restrict__ lnb,
    const float* __restrict__ nw1, const float* __restrict__ nb1,
    const float* __restrict__ nwc, const float* __restrict__ nwcb,
    float* __restrict__ hl, float* __restrict__ x2)
{
  __shared__ unsigned int A[16 * ASTR];
  __shared__ float PS[4][16], PQ[4][16];
  const int tid = threadIdx.x, lane = tid & 63, w = tid >> 6;
  const int tilebase = blockIdx.x * 16;
  const int c = lane & 15, q = lane >> 4;
  const int n = 16 * w + c;   // this wave's output column

  // early prefetch (epilogue operands)
  float x2v[4];
#pragma unroll
  for (int r = 0; r < 4; ++r)
    x2v[r] = x2[(tilebase + 4 * q + r) * 64 + n];
  float lg = lng[n], lb = lnb[n], vb = b2[n];

  // stage agg tile (16x64) packed: each thread 4 consecutive floats
  {
    int i = tid * 4;
    int row = i >> 6, col = i & 63;
    float4 v = *(const float4*)(agg + tilebase * 64 + i);
    uint4v pv;
    pv[0] = bsplit(v.x); pv[1] = bsplit(v.y); pv[2] = bsplit(v.z); pv[3] = bsplit(v.w);
    *(uint4v*)(A + row * ASTR + col) = pv;
  }
  __syncthreads();

  f32x4 acc = gemm16(A, w2, n, c, q);

  float S[4];
#pragma unroll
  for (int r = 0; r < 4; ++r) S[r] = acc[r] + vb + x2v[r];

  // per-wave partial (sum, sumsq) over this wave's 16 columns
#pragma unroll
  for (int r = 0; r < 4; ++r) {
    float s1 = S[r], s2 = S[r] * S[r];
#pragma unroll
    for (int m = 1; m < 16; m <<= 1) {
      s1 += __shfl_xor(s1, m, 64);
      s2 += __shfl_xor(s2, m, 64);
    }
    if (c == 0) { PS[w][4 * q + r] = s1; PQ[w][4 * q + r] = s2; }
  }
  __syncthreads();

  // finalize LN + gelu, write h transposed-packed into A
#pragma unroll
  for (int r = 0; r < 4; ++r) {
    int row = 4 * q + r;
    float sum = PS[0][row] + PS[1][row] + PS[2][row] + PS[3][row];
    float sq  = PQ[0][row] + PQ[1][row] + PQ[2][row] + PQ[3][row];
    float mean = sum * (1.0f / 64.0f);
    float var = sq * (1.0f / 64.0f) - mean * mean;
    float hv = (S[r] - mean) * rsqrtf(var + 1e-5f) * lg + lb;
    hv = gelu_exact(hv);
    A[row * ASTR + n] = bsplit(hv);
  }
  __syncthreads();

  f32x4 a1v = gemm16(A, nw1, n, c, q);
  float b1v = nb1[n];
#pragma unroll
  for (int r = 0; r < 4; ++r)
    hl[(tilebase + 4 * q + r) * 64 + n] = a1v[r] + b1v;

  f32x4 a2v = gemm16(A, nwc, n, c, q);
  float wcbv = nwcb[n];
#pragma unroll
  for (int r = 0; r < 4; ++r)
    x2[(tilebase + 4 * q + r) * 64 + n] = a2v[r] + wcbv;
}

// ---------------------------------------------------------------------------
// post (layer 2) + head: h = LN(agg@W2.T + b2 + x2);
// t = gelu(h@fc1.T + fc1b); out = t@fc2.T + fc2b. Wave w owns fc1 rows 32w..32w+31.
// ---------------------------------------------------------------------------
__global__ __launch_bounds__(256) void k_post_last(
    const float* __restrict__ agg,
    const float* __restrict__ w2, const float* __restrict__ b2,
    const float* __restrict__ lng, const float* __restrict__ lnb,
    const float* __restrict__ x2,
    const float* __restrict__ fc1w, const float* __restrict__ fc1b,
    const float* __restrict__ fw2, const float* __restrict__ fb2,
    float* __restrict__ out)
{
  __shared__ unsigned int A[16 * ASTR];
  __shared__ float PS[4][16], PQ[4][16];
  const int tid = threadIdx.x, lane = tid & 63, w = tid >> 6;
  const int tilebase = blockIdx.x * 16;
  const int c = lane & 15, q = lane >> 4;
  const int n = 16 * w + c;

  float x2v[4];
#pragma unroll
  for (int r = 0; r < 4; ++r)
    x2v[r] = x2[(tilebase + 4 * q + r) * 64 + n];
  float lg = lng[n], lb = lnb[n], vb = b2[n];

  {
    int i = tid * 4;
    int row = i >> 6, col = i & 63;
    float4 v = *(const float4*)(agg + tilebase * 64 + i);
    uint4v pv;
    pv[0] = bsplit(v.x); pv[1] = bsplit(v.y); pv[2] = bsplit(v.z); pv[3] = bsplit(v.w);
    *(uint4v*)(A + row * ASTR + col) = pv;
  }
  __syncthreads();

  f32x4 acc = gemm16(A, w2, n, c, q);

  float S[4];
#pragma unroll
  for (int r = 0; r < 4; ++r) S[r] = acc[r] + vb + x2v[r];

#pragma unroll
  for (int r = 0; r < 4; ++r) {
    float s1 = S[r], s2 = S[r] * S[r];
#pragma unroll
    for (int m = 1; m < 16; m <<= 1) {
      s1 += __shfl_xor(s1, m, 64);
      s2 += __shfl_xor(s2, m, 64);
    }
    if (c == 0) { PS[w][4 * q + r] = s1; PQ[w][4 * q + r] = s2; }
  }
  __syncthreads();

#pragma unroll
  for (int r = 0; r < 4; ++r) {
    int row = 4 * q + r;
    float sum = PS[0][row] + PS[1][row] + PS[2][row] + PS[3][row];
    float sq  = PQ[0][row] + PQ[1][row] + PQ[2][row] + PQ[3][row];
    float mean = sum * (1.0f / 64.0f);
    float var = sq * (1.0f / 64.0f) - mean * mean;
    float hv = (S[r] - mean) * rsqrtf(var + 1e-5f) * lg + lb;   // no gelu
    A[row * ASTR + n] = bsplit(hv);
  }
  __syncthreads();

  // head: wave w covers fc1 rows 32w + {c, 16+c}
  Frag ha0 = load_afrag(A + c * ASTR + 8 * q);
  Frag ha1 = load_afrag(A + c * ASTR + 32 + 8 * q);
  float p[4] = {0.f, 0.f, 0.f, 0.f};
#pragma unroll
  for (int half = 0; half < 2; ++half) {
    int row = 32 * w + 16 * half + c;
    Frag b0 = load_bfrag(fc1w + row * 64 + 8 * q);
    Frag b1 = load_bfrag(fc1w + row * 64 + 32 + 8 * q);
    f32x4 a = {0.f, 0.f, 0.f, 0.f};
    a = mfma3(ha0, b0, a);
    a = mfma3(ha1, b1, a);
    float fbv = fc1b[row], fwv = fw2[row];
#pragma unroll
    for (int r = 0; r < 4; ++r) p[r] += gelu_exact(a[r] + fbv) * fwv;
  }
#pragma unroll
  for (int r = 0; r < 4; ++r) {
    float s = p[r];
#pragma unroll
    for (int m = 1; m < 16; m <<= 1) s += __shfl_xor(s, m, 64);
    if (c == 0) PS[w][4 * q + r] = s;
  }
  __syncthreads();
  if (tid < 16)
    out[tilebase + tid] = PS[0][tid] + PS[1][tid] + PS[2][tid] + PS[3][tid] + fb2[0];
}

// ---------------------------------------------------------------------------
extern "C" void kernel_launch(void* const* d_in, const int* in_sizes, int n_in,
                              void* d_out, int out_size, void* d_ws, size_t ws_size,
                              hipStream_t stream) {
  const float* x     = (const float*)d_in[0];
  const int* ei      = (const int*)d_in[1];
  const float* fc0_w = (const float*)d_in[2];
  const float* fc0_b = (const float*)d_in[3];
  const float* ln0_g = (const float*)d_in[4];
  const float* ln0_b = (const float*)d_in[5];
  const float* gg_fc1_w = (const float*)d_in[6];
  const float* gg_fc1_b = (const float*)d_in[7];
  const float* gg_fc2_w = (const float*)d_in[8];
  const float* gg_fc2_b = (const float*)d_in[9];
  const float* gg_weight = (const float*)d_in[10];
  const float* gg_freq   = (const float*)d_in[11];
  const float* wc_w = (const float*)d_in[12];
  const float* wc_b = (const float*)d_in[13];
  const float* ln_g = (const float*)d_in[14];
  const float* ln_b = (const float*)d_in[15];
  const float* fc1_w = (const float*)d_in[16];
  const float* fc1_b = (const float*)d_in[17];
  const float* fc2_w = (const float*)d_in[18];
  const float* fc2_b = (const float*)d_in[19];

  char* ws = (char*)d_ws;
  size_t off = 0;
  auto alloc = [&](size_t bytes) -> void* {
    void* p = ws + off;
    off = (off + bytes + 255) & ~(size_t)255;
    return p;
  };
  float2* grid2   = (float2*)alloc((size_t)M_NODES * 8);
  float*  gwf     = (float*)alloc((size_t)M_NODES * 4);
  float*  hl      = (float*)alloc((size_t)M_NODES * 64 * 4);
  float*  agg     = (float*)alloc((size_t)M_NODES * 64 * 4);
  float*  x2      = (float*)alloc((size_t)M_NODES * 64 * 4);
  int*    cnt     = (int*)alloc((size_t)M_NODES * 4);
  int*    cursor  = (int*)alloc((size_t)M_NODES * 4);
  int*    row_st  = (int*)alloc((size_t)(M_NODES + 1) * 4);
  float4* rec     = (float4*)alloc((size_t)E_EDGES * 16);
  (void)ws_size; (void)in_sizes; (void)n_in; (void)out_size;

  hipMemsetAsync(cnt, 0, (size_t)M_NODES * 4, stream);

  k_init<<<M_NODES / 16, 256, 0, stream>>>(x, fc0_w, fc0_b, ln0_g, ln0_b,
                                           gg_fc1_w, gg_fc1_b, wc_w, wc_b,
                                           grid2, gwf, hl, x2);
  k_count<<<E_EDGES / 256, 256, 0, stream>>>(ei, cnt);
  k_scan<<<1, 1024, 0, stream>>>(cnt, row_st, cursor);
  k_scatter<<<E_EDGES / 256, 256, 0, stream>>>(ei, grid2, gwf, cursor, rec);

  for (int l = 0; l < 3; ++l) {
    k_agg<<<M_NODES / 4, 256, 0, stream>>>(rec, row_st, hl,
                                           gg_weight + l * 64, gg_freq + l * 128, agg);
    if (l < 2) {
      k_post_mid<<<M_NODES / 16, 256, 0, stream>>>(
          agg,
          gg_fc2_w + l * 4096, gg_fc2_b + l * 64,
          ln_g + l * 64, ln_b + l * 64,
          gg_fc1_w + (l + 1) * 4096, gg_fc1_b + (l + 1) * 64,
          wc_w + (l + 1) * 4096, wc_b + (l + 1) * 64,
          hl, x2);
    } else {
      k_post_last<<<M_NODES / 16, 256, 0, stream>>>(
          agg,
          gg_fc2_w + l * 4096, gg_fc2_b + l * 64,
          ln_g + l * 64, ln_b + l * 64,
          x2,
          fc1_w, fc1_b, fc2_w, fc2_b,
          (float*)d_out);
    }
  }
}

// Round 6
// 260.485 us; speedup vs baseline: 1.9122x; 1.1054x over previous
//
#include <hip/hip_runtime.h>
#include <hip/hip_bf16.h>

#define M_NODES 16384
#define E_EDGES 524288
#define ASTR 68   // uint stride of LDS A rows

typedef short short8 __attribute__((ext_vector_type(8)));
typedef float f32x4 __attribute__((ext_vector_type(4)));
typedef unsigned int uint4v __attribute__((ext_vector_type(4)));

// packed-weight regions (float offsets): [w1 3x4096 | wc 3x4096 | w2 3x4096 | fc1 8192]
#define PK_W1 0
#define PK_WC 12288
#define PK_W2 24576
#define PK_FC1 36864
#define PK_TOTAL 45056

static __device__ __forceinline__ float wredsum(float v) {
#pragma unroll
  for (int o = 32; o > 0; o >>= 1) v += __shfl_xor(v, o, 64);
  return v;
}

static __device__ __forceinline__ float gelu_exact(float x) {
  return 0.5f * x * (1.0f + erff(x * 0.70710678118654752440f));
}

// split fp32 -> (bf16 hi | bf16 lo) packed in one uint
static __device__ __forceinline__ unsigned int bsplit(float x) {
  unsigned int u = __float_as_uint(x);
  unsigned int hb = (u + 0x7FFFu + ((u >> 16) & 1u)) >> 16;
  float hf = __uint_as_float(hb << 16);
  float r = x - hf;
  unsigned int v = __float_as_uint(r);
  unsigned int lb = (v + 0x7FFFu + ((v >> 16) & 1u)) >> 16;
  return (hb & 0xFFFFu) | (lb << 16);
}

struct Frag { short8 hi, lo; };

static __device__ __forceinline__ Frag load_afrag(const unsigned int* a) {
  uint4v u0 = *(const uint4v*)a;
  uint4v u1 = *(const uint4v*)(a + 4);
  Frag f;
#pragma unroll
  for (int j = 0; j < 4; ++j) {
    f.hi[j]     = (short)(u0[j] & 0xFFFFu);
    f.lo[j]     = (short)(u0[j] >> 16);
    f.hi[j + 4] = (short)(u1[j] & 0xFFFFu);
    f.lo[j + 4] = (short)(u1[j] >> 16);
  }
  return f;
}

// raw fp32 weights -> fragments (used only in front kernel's init branch)
static __device__ __forceinline__ Frag load_bfrag(const float* __restrict__ w) {
  float4 w0 = *(const float4*)w;
  float4 w1 = *(const float4*)(w + 4);
  float v[8] = {w0.x, w0.y, w0.z, w0.w, w1.x, w1.y, w1.z, w1.w};
  Frag f;
#pragma unroll
  for (int j = 0; j < 8; ++j) {
    unsigned int p = bsplit(v[j]);
    f.hi[j] = (short)(p & 0xFFFFu);
    f.lo[j] = (short)(p >> 16);
  }
  return f;
}

static __device__ __forceinline__ f32x4 mfma3(const Frag& a, const Frag& b, f32x4 c) {
  c = __builtin_amdgcn_mfma_f32_16x16x32_bf16(a.hi, b.hi, c, 0, 0, 0);
  c = __builtin_amdgcn_mfma_f32_16x16x32_bf16(a.lo, b.hi, c, 0, 0, 0);
  c = __builtin_amdgcn_mfma_f32_16x16x32_bf16(a.hi, b.lo, c, 0, 0, 0);
  return c;
}

// packed-weight B fragment: hi shorts at P[n*64+off], lo at P[S+n*64+off]
static __device__ __forceinline__ Frag load_bpk(const short* __restrict__ P, int S, int n, int off) {
  Frag f;
  f.hi = *(const short8*)(P + n * 64 + off);
  f.lo = *(const short8*)(P + S + n * 64 + off);
  return f;
}

static __device__ __forceinline__ f32x4 gemm16p(const unsigned int* __restrict__ A,
                                                const short* __restrict__ P, int S,
                                                int n, int c, int q) {
  Frag a0 = load_afrag(A + c * ASTR + 8 * q);
  Frag a1 = load_afrag(A + c * ASTR + 32 + 8 * q);
  Frag b0 = load_bpk(P, S, n, 8 * q);
  Frag b1 = load_bpk(P, S, n, 32 + 8 * q);
  f32x4 acc = {0.f, 0.f, 0.f, 0.f};
  acc = mfma3(a0, b0, acc);
  acc = mfma3(a1, b1, acc);
  return acc;
}

// ---------------------------------------------------------------------------
// front kernel: blocks [0,1024) init; [1024,3072) edge count; [3072,3248) weight pack
// ---------------------------------------------------------------------------
__global__ __launch_bounds__(256) void k_front(
    const float* __restrict__ x,
    const float* __restrict__ fc0_w, const float* __restrict__ fc0_b,
    const float* __restrict__ ln0_g, const float* __restrict__ ln0_b,
    const float* __restrict__ gg_fc1_w, const float* __restrict__ gg_fc1_b,
    const float* __restrict__ wc_w, const float* __restrict__ wc_b,
    const float* __restrict__ gg_fc2_w, const float* __restrict__ fc1_w,
    const int* __restrict__ ei, int* __restrict__ cnt, short* __restrict__ pk,
    float2* __restrict__ grid2, float* __restrict__ gwf,
    float* __restrict__ hl, float* __restrict__ x2T)
{
  __shared__ unsigned int A[16 * ASTR];
  const int bid = blockIdx.x;
  const int tid = threadIdx.x;

  if (bid >= 3072) {              // ---- pack branch
    int i = (bid - 3072) * 256 + tid;   // [0, 45056)
    float v = (i < PK_WC)  ? gg_fc1_w[i]
            : (i < PK_W2)  ? wc_w[i - PK_WC]
            : (i < PK_FC1) ? gg_fc2_w[i - PK_W2]
                           : fc1_w[i - PK_FC1];
    int mb, sz;
    if (i < PK_FC1) { mb = i & ~4095; sz = 4096; } else { mb = PK_FC1; sz = 8192; }
    int k = i - mb;
    unsigned int p = bsplit(v);
    pk[2 * mb + k]      = (short)(p & 0xFFFFu);
    pk[2 * mb + sz + k] = (short)(p >> 16);
    return;
  }
  if (bid >= 1024) {              // ---- count branch
    int e = (bid - 1024) * 256 + tid;
    atomicAdd(&cnt[ei[E_EDGES + e]], 1);
    return;
  }

  // ---- init branch: 16 nodes/block
  const int lane = tid & 63, w = tid >> 6;
  const int tilebase = bid * 16;

  float fw0 = fc0_w[lane * 4 + 0], fw1 = fc0_w[lane * 4 + 1];
  float fw2v = fc0_w[lane * 4 + 2], fw3 = fc0_w[lane * 4 + 3];
  float fb = fc0_b[lane], g0 = ln0_g[lane], bb0 = ln0_b[lane];

#pragma unroll
  for (int i = 0; i < 4; ++i) {
    int node = tilebase + 4 * w + i;
    float xv0 = x[node * 5 + 0], xv1 = x[node * 5 + 1], xv2 = x[node * 5 + 2];
    float xv3 = x[node * 5 + 3], xv4 = x[node * 5 + 4];
    float acc = fb + xv0 * fw0 + xv1 * fw1 + xv2 * fw2v + xv3 * fw3;
    float mean = wredsum(acc) * (1.0f / 64.0f);
    float d = acc - mean;
    float var = wredsum(d * d) * (1.0f / 64.0f);
    float hv = d * rsqrtf(var + 1e-5f) * g0 + bb0;
    A[(4 * w + i) * ASTR + lane] = bsplit(hv);
    if (lane == 0) { grid2[node] = make_float2(xv2, xv3); gwf[node] = xv4; }
  }
  __syncthreads();

  const int c = lane & 15, q = lane >> 4;
  const int n = 16 * w + c;

  // hl0 = h0 @ W1[0].T + b1[0]  (raw fp32 weights: pack not yet visible)
  {
    Frag a0 = load_afrag(A + c * ASTR + 8 * q);
    Frag a1 = load_afrag(A + c * ASTR + 32 + 8 * q);
    Frag b0 = load_bfrag(gg_fc1_w + n * 64 + 8 * q);
    Frag b1 = load_bfrag(gg_fc1_w + n * 64 + 32 + 8 * q);
    f32x4 acc = {0.f, 0.f, 0.f, 0.f};
    acc = mfma3(a0, b0, acc);
    acc = mfma3(a1, b1, acc);
    float b1v = gg_fc1_b[n];
#pragma unroll
    for (int r = 0; r < 4; ++r)
      hl[(tilebase + 4 * q + r) * 64 + n] = acc[r] + b1v;

    Frag c0 = load_bfrag(wc_w + n * 64 + 8 * q);
    Frag c1 = load_bfrag(wc_w + n * 64 + 32 + 8 * q);
    f32x4 ac2 = {0.f, 0.f, 0.f, 0.f};
    ac2 = mfma3(a0, c0, ac2);
    ac2 = mfma3(a1, c1, ac2);
    float wcbv = wc_b[n];
    *(float4*)(x2T + n * M_NODES + tilebase + 4 * q) =
        make_float4(ac2[0] + wcbv, ac2[1] + wcbv, ac2[2] + wcbv, ac2[3] + wcbv);
  }
}

// ---------------------------------------------------------------------------
__global__ __launch_bounds__(1024) void k_scan(const int* __restrict__ cnt,
                                               int* __restrict__ row_start,
                                               int* __restrict__ cursor)
{
  const int PER = M_NODES / 1024;
  const int t = threadIdx.x;
  const int base = t * PER;
  int local[PER];
  int s = 0;
#pragma unroll
  for (int k = 0; k < PER; ++k) { local[k] = cnt[base + k]; s += local[k]; }

  __shared__ int part[1024];
  part[t] = s;
  __syncthreads();
  for (int off = 1; off < 1024; off <<= 1) {
    int v = (t >= off) ? part[t - off] : 0;
    __syncthreads();
    part[t] += v;
    __syncthreads();
  }
  int run = part[t] - s;
#pragma unroll
  for (int k = 0; k < PER; ++k) {
    row_start[base + k] = run;
    cursor[base + k] = run;
    run += local[k];
  }
  if (t == 1023) row_start[M_NODES] = run;
}

__global__ __launch_bounds__(256) void k_scatter(
    const int* __restrict__ ei, const float2* __restrict__ grid2,
    const float* __restrict__ gwf, int* __restrict__ cursor,
    float4* __restrict__ rec)
{
  int e = blockIdx.x * 256 + threadIdx.x;
  if (e < E_EDGES) {
    int s = ei[e];
    int dd = ei[E_EDGES + e];
    int pos = atomicAdd(&cursor[dd], 1);
    float2 gs = grid2[s], gd = grid2[dd];
    rec[pos] = make_float4(gs.x - gd.x, gs.y - gd.y, gwf[s], __int_as_float(s));
  }
}

// ---------------------------------------------------------------------------
// edge aggregation: chunk-64 coalesced rec -> LDS; groups of 8 ping-pong
// (8 independent ds_read_b128 broadcasts + 8 independent hl gathers in flight)
// ---------------------------------------------------------------------------
__global__ __launch_bounds__(256) void k_agg(
    const float4* __restrict__ rec, const int* __restrict__ row_start,
    const float* __restrict__ hl,
    const float* __restrict__ gw, const float* __restrict__ freq,
    unsigned int* __restrict__ aggp)
{
  __shared__ float4 LR[4][64];
  const int lane = threadIdx.x & 63;
  const int w = threadIdx.x >> 6;
  const int node = blockIdx.x * 4 + w;

  const float wv = gw[lane];
  const float nwl2 = -wv * 1.44269504088896340736f;
  const float lc = log2f(wv * 0.31830988618379067154f);
  const float f0s = freq[lane] * 0.15915494309189533577f;
  const float f1s = freq[64 + lane] * 0.15915494309189533577f;

  const int beg = row_start[node];
  const int end = row_start[node + 1];
  const float* hlp = hl + lane;
  float4* LRw = LR[w];   // wave-private: no barrier needed

  float acc = 0.0f;

  for (int base = beg; base < end; base += 64) {
    const int cn = min(64, end - base);
    if (lane < cn) LRw[lane] = rec[base + lane];

    float4 RA[8], RB[8];
    float HA[8], HB[8];

    auto ldg = [&](float4* R, float* H, int off) {
#pragma unroll
      for (int u = 0; u < 8; ++u) {
        int j = off + u; j = (j < cn) ? j : (cn - 1);
        R[u] = LRw[j];
      }
#pragma unroll
      for (int u = 0; u < 8; ++u)
        H[u] = hlp[__float_as_int(R[u].w) * 64];
    };
    auto cmp8 = [&](const float4* R, const float* H, int off) {
#pragma unroll
      for (int u = 0; u < 8; ++u) {
        if (off + u < cn) {
          float dist2 = __builtin_fmaf(R[u].x, R[u].x, R[u].y * R[u].y);
          float gs = __builtin_amdgcn_exp2f(__builtin_fmaf(nwl2, dist2, lc));
          float rev = __builtin_fmaf(R[u].x, f0s, R[u].y * f1s);
          float fo = __builtin_amdgcn_sinf(__builtin_amdgcn_fractf(rev));
          acc = __builtin_fmaf(gs * fo * H[u], R[u].z, acc);
        }
      }
    };

    const int Gp = (cn + 7) >> 3;
    ldg(RA, HA, 0);
    int g = 0;
    for (; g + 2 < Gp; g += 2) {
      ldg(RB, HB, 8 * (g + 1));
      cmp8(RA, HA, 8 * g);
      ldg(RA, HA, 8 * (g + 2));
      cmp8(RB, HB, 8 * (g + 1));
    }
    if (g + 1 < Gp) {
      ldg(RB, HB, 8 * (g + 1));
      cmp8(RA, HA, 8 * g);
      cmp8(RB, HB, 8 * (g + 1));
    } else {
      cmp8(RA, HA, 8 * g);
    }
  }
  aggp[node * 64 + lane] = bsplit(acc);
}

// ---------------------------------------------------------------------------
// post (layers 0,1): S = agg@W2.T + b2 + x2; h = gelu(LN(S));
// hl = h@W1n.T + b1n; x2 = h@Wcn.T + wcbn.  Packed weights, x2 transposed.
// ---------------------------------------------------------------------------
__global__ __launch_bounds__(256) void k_post_mid(
    const unsigned int* __restrict__ aggp,
    const short* __restrict__ pw2, const float* __restrict__ b2,
    const float* __restrict__ lng, const float* __restrict__ lnb,
    const short* __restrict__ pnw1, const float* __restrict__ nb1,
    const short* __restrict__ pnwc, const float* __restrict__ nwcb,
    float* __restrict__ hl, float* __restrict__ x2T)
{
  __shared__ unsigned int A[16 * ASTR];
  __shared__ float PS[4][16], PQ[4][16];
  const int tid = threadIdx.x, lane = tid & 63, w = tid >> 6;
  const int tilebase = blockIdx.x * 16;
  const int c = lane & 15, q = lane >> 4;
  const int n = 16 * w + c;

  // early independent prefetches
  float4 x2v = *(const float4*)(x2T + n * M_NODES + tilebase + 4 * q);
  float lg = lng[n], lb = lnb[n], vb = b2[n];
  float b1v = nb1[n], wcbv = nwcb[n];
  Frag wb0 = load_bpk(pw2, 4096, n, 8 * q);        // preload w2 frags before barrier
  Frag wb1 = load_bpk(pw2, 4096, n, 32 + 8 * q);

  {
    int i = tid * 4;
    *(uint4v*)(A + (i >> 6) * ASTR + (i & 63)) = *(const uint4v*)(aggp + tilebase * 64 + i);
  }
  __syncthreads();

  Frag a0 = load_afrag(A + c * ASTR + 8 * q);
  Frag a1 = load_afrag(A + c * ASTR + 32 + 8 * q);
  f32x4 acc = {0.f, 0.f, 0.f, 0.f};
  acc = mfma3(a0, wb0, acc);
  acc = mfma3(a1, wb1, acc);

  float S[4];
#pragma unroll
  for (int r = 0; r < 4; ++r) S[r] = acc[r] + vb + x2v[r];

#pragma unroll
  for (int r = 0; r < 4; ++r) {
    float s1 = S[r], s2 = S[r] * S[r];
#pragma unroll
    for (int m = 1; m < 16; m <<= 1) {
      s1 += __shfl_xor(s1, m, 64);
      s2 += __shfl_xor(s2, m, 64);
    }
    if (c == 0) { PS[w][4 * q + r] = s1; PQ[w][4 * q + r] = s2; }
  }
  __syncthreads();

#pragma unroll
  for (int r = 0; r < 4; ++r) {
    int row = 4 * q + r;
    float sum = PS[0][row] + PS[1][row] + PS[2][row] + PS[3][row];
    float sq  = PQ[0][row] + PQ[1][row] + PQ[2][row] + PQ[3][row];
    float mean = sum * (1.0f / 64.0f);
    float var = sq * (1.0f / 64.0f) - mean * mean;
    float hv = (S[r] - mean) * rsqrtf(var + 1e-5f) * lg + lb;
    hv = gelu_exact(hv);
    A[row * ASTR + n] = bsplit(hv);
  }
  __syncthreads();   // h fully written before any wave's next GEMM reads (race fix)

  f32x4 h1 = gemm16p(A, pnw1, 4096, n, c, q);
#pragma unroll
  for (int r = 0; r < 4; ++r)
    hl[(tilebase + 4 * q + r) * 64 + n] = h1[r] + b1v;

  f32x4 hx = gemm16p(A, pnwc, 4096, n, c, q);
  *(float4*)(x2T + n * M_NODES + tilebase + 4 * q) =
      make_float4(hx[0] + wcbv, hx[1] + wcbv, hx[2] + wcbv, hx[3] + wcbv);
}

// ---------------------------------------------------------------------------
// post (layer 2) + head
// ---------------------------------------------------------------------------
__global__ __launch_bounds__(256) void k_post_last(
    const unsigned int* __restrict__ aggp,
    const short* __restrict__ pw2, const float* __restrict__ b2,
    const float* __restrict__ lng, const float* __restrict__ lnb,
    const float* __restrict__ x2T,
    const short* __restrict__ pfc1, const float* __restrict__ fc1b,
    const float* __restrict__ fw2, const float* __restrict__ fb2,
    float* __restrict__ out)
{
  __shared__ unsigned int A[16 * ASTR];
  __shared__ float PS[4][16], PQ[4][16];
  const int tid = threadIdx.x, lane = tid & 63, w = tid >> 6;
  const int tilebase = blockIdx.x * 16;
  const int c = lane & 15, q = lane >> 4;
  const int n = 16 * w + c;

  float4 x2v = *(const float4*)(x2T + n * M_NODES + tilebase + 4 * q);
  float lg = lng[n], lb = lnb[n], vb = b2[n];
  Frag wb0 = load_bpk(pw2, 4096, n, 8 * q);
  Frag wb1 = load_bpk(pw2, 4096, n, 32 + 8 * q);

  {
    int i = tid * 4;
    *(uint4v*)(A + (i >> 6) * ASTR + (i & 63)) = *(const uint4v*)(aggp + tilebase * 64 + i);
  }
  __syncthreads();

  Frag a0 = load_afrag(A + c * ASTR + 8 * q);
  Frag a1 = load_afrag(A + c * ASTR + 32 + 8 * q);
  f32x4 acc = {0.f, 0.f, 0.f, 0.f};
  acc = mfma3(a0, wb0, acc);
  acc = mfma3(a1, wb1, acc);

  float S[4];
#pragma unroll
  for (int r = 0; r < 4; ++r) S[r] = acc[r] + vb + x2v[r];

#pragma unroll
  for (int r = 0; r < 4; ++r) {
    float s1 = S[r], s2 = S[r] * S[r];
#pragma unroll
    for (int m = 1; m < 16; m <<= 1) {
      s1 += __shfl_xor(s1, m, 64);
      s2 += __shfl_xor(s2, m, 64);
    }
    if (c == 0) { PS[w][4 * q + r] = s1; PQ[w][4 * q + r] = s2; }
  }
  __syncthreads();

#pragma unroll
  for (int r = 0; r < 4; ++r) {
    int row = 4 * q + r;
    float sum = PS[0][row] + PS[1][row] + PS[2][row] + PS[3][row];
    float sq  = PQ[0][row] + PQ[1][row] + PQ[2][row] + PQ[3][row];
    float mean = sum * (1.0f / 64.0f);
    float var = sq * (1.0f / 64.0f) - mean * mean;
    float hv = (S[r] - mean) * rsqrtf(var + 1e-5f) * lg + lb;   // no gelu
    A[row * ASTR + n] = bsplit(hv);
  }
  __syncthreads();

  // head: wave w covers fc1 rows 32w + {c, 16+c}
  Frag ha0 = load_afrag(A + c * ASTR + 8 * q);
  Frag ha1 = load_afrag(A + c * ASTR + 32 + 8 * q);
  float p[4] = {0.f, 0.f, 0.f, 0.f};
#pragma unroll
  for (int half = 0; half < 2; ++half) {
    int row = 32 * w + 16 * half + c;
    Frag b0 = load_bpk(pfc1, 8192, row, 8 * q);
    Frag b1 = load_bpk(pfc1, 8192, row, 32 + 8 * q);
    f32x4 a = {0.f, 0.f, 0.f, 0.f};
    a = mfma3(ha0, b0, a);
    a = mfma3(ha1, b1, a);
    float fbv = fc1b[row], fwv = fw2[row];
#pragma unroll
    for (int r = 0; r < 4; ++r) p[r] += gelu_exact(a[r] + fbv) * fwv;
  }
#pragma unroll
  for (int r = 0; r < 4; ++r) {
    float s = p[r];
#pragma unroll
    for (int m = 1; m < 16; m <<= 1) s += __shfl_xor(s, m, 64);
    if (c == 0) PS[w][4 * q + r] = s;
  }
  __syncthreads();
  if (tid < 16)
    out[tilebase + tid] = PS[0][tid] + PS[1][tid] + PS[2][tid] + PS[3][tid] + fb2[0];
}

// ---------------------------------------------------------------------------
extern "C" void kernel_launch(void* const* d_in, const int* in_sizes, int n_in,
                              void* d_out, int out_size, void* d_ws, size_t ws_size,
                              hipStream_t stream) {
  const float* x     = (const float*)d_in[0];
  const int* ei      = (const int*)d_in[1];
  const float* fc0_w = (const float*)d_in[2];
  const float* fc0_b = (const float*)d_in[3];
  const float* ln0_g = (const float*)d_in[4];
  const float* ln0_b = (const float*)d_in[5];
  const float* gg_fc1_w = (const float*)d_in[6];
  const float* gg_fc1_b = (const float*)d_in[7];
  const float* gg_fc2_w = (const float*)d_in[8];
  const float* gg_fc2_b = (const float*)d_in[9];
  const float* gg_weight = (const float*)d_in[10];
  const float* gg_freq   = (const float*)d_in[11];
  const float* wc_w = (const float*)d_in[12];
  const float* wc_b = (const float*)d_in[13];
  const float* ln_g = (const float*)d_in[14];
  const float* ln_b = (const float*)d_in[15];
  const float* fc1_w = (const float*)d_in[16];
  const float* fc1_b = (const float*)d_in[17];
  const float* fc2_w = (const float*)d_in[18];
  const float* fc2_b = (const float*)d_in[19];

  char* ws = (char*)d_ws;
  size_t off = 0;
  auto alloc = [&](size_t bytes) -> void* {
    void* p = ws + off;
    off = (off + bytes + 255) & ~(size_t)255;
    return p;
  };
  float2* grid2 = (float2*)alloc((size_t)M_NODES * 8);
  float*  gwf   = (float*)alloc((size_t)M_NODES * 4);
  float*  hl    = (float*)alloc((size_t)M_NODES * 64 * 4);
  unsigned int* aggp = (unsigned int*)alloc((size_t)M_NODES * 64 * 4);
  float*  x2T   = (float*)alloc((size_t)M_NODES * 64 * 4);
  int*    cnt   = (int*)alloc((size_t)M_NODES * 4);
  int*    cursor= (int*)alloc((size_t)M_NODES * 4);
  int*    row_st= (int*)alloc((size_t)(M_NODES + 1) * 4);
  float4* rec   = (float4*)alloc((size_t)E_EDGES * 16);
  short*  pk    = (short*)alloc((size_t)PK_TOTAL * 2 * 2);
  (void)ws_size; (void)in_sizes; (void)n_in; (void)out_size;

  hipMemsetAsync(cnt, 0, (size_t)M_NODES * 4, stream);

  k_front<<<3248, 256, 0, stream>>>(x, fc0_w, fc0_b, ln0_g, ln0_b,
                                    gg_fc1_w, gg_fc1_b, wc_w, wc_b,
                                    gg_fc2_w, fc1_w,
                                    ei, cnt, pk, grid2, gwf, hl, x2T);
  k_scan<<<1, 1024, 0, stream>>>(cnt, row_st, cursor);
  k_scatter<<<E_EDGES / 256, 256, 0, stream>>>(ei, grid2, gwf, cursor, rec);

  for (int l = 0; l < 3; ++l) {
    k_agg<<<M_NODES / 4, 256, 0, stream>>>(rec, row_st, hl,
                                           gg_weight + l * 64, gg_freq + l * 128, aggp);
    const short* pw2 = pk + 2 * (PK_W2 + l * 4096);
    if (l < 2) {
      k_post_mid<<<M_NODES / 16, 256, 0, stream>>>(
          aggp, pw2, gg_fc2_b + l * 64,
          ln_g + l * 64, ln_b + l * 64,
          pk + 2 * (PK_W1 + (l + 1) * 4096), gg_fc1_b + (l + 1) * 64,
          pk + 2 * (PK_WC + (l + 1) * 4096), wc_b + (l + 1) * 64,
          hl, x2T);
    } else {
      k_post_last<<<M_NODES / 16, 256, 0, stream>>>(
          aggp, pw2, gg_fc2_b + l * 64,
          ln_g + l * 64, ln_b + l * 64,
          x2T,
          pk + 2 * PK_FC1, fc1_b, fc2_w, fc2_b,
          (float*)d_out);
    }
  }
}